// Round 1
// baseline (3196.022 us; speedup 1.0000x reference)
//
#include <hip/hip_runtime.h>

#define NN 50000
#define NE 800000
#define DD 128

// ---------------------------------------------------------------------------
// Index width detection: reference says int64, harness doc says int arrives as
// int32. Detect on-device: if the buffer is int32 pairs, reading as u64 gives
// values >= 2^32 almost surely within the first 64 entries (hi word is the
// next random index). Genuine int64 indices (< 50000) never do.
// ---------------------------------------------------------------------------
__global__ void detect_k(const void* __restrict__ ei, int* __restrict__ flag) {
  if (threadIdx.x == 0 && blockIdx.x == 0) {
    const unsigned long long* p = (const unsigned long long*)ei;
    int is64 = 1;
    for (int i = 0; i < 64; ++i)
      if (p[i] >= (1ull << 32)) { is64 = 0; break; }
    *flag = is64;
  }
}

__device__ __forceinline__ int ld_idx(const void* ei, int is64, long long i) {
  return is64 ? (int)((const long long*)ei)[i] : ((const int*)ei)[i];
}

// ---------------------------------------------------------------------------
// Degree count: cnt[tgt[e]] += 1  (float, exact for counts << 2^24)
// ---------------------------------------------------------------------------
__global__ __launch_bounds__(256) void count_k(const void* __restrict__ ei,
                                               const int* __restrict__ flag,
                                               float* __restrict__ cnt) {
  int e = blockIdx.x * 256 + threadIdx.x;
  int is64 = *flag;
  int d = ld_idx(ei, is64, (long long)NE + e);
  atomicAdd(&cnt[d], 1.0f);
}

// ---------------------------------------------------------------------------
// Scatter-add aggregation: agg[tgt[e]][:] += feat[src[e]][:]
// 32 threads per edge, each handles 4 contiguous floats (float4 gather,
// 4 scalar fp32 global atomics). Gather is fully coalesced (512 B / 32 lanes).
// ---------------------------------------------------------------------------
__global__ __launch_bounds__(256) void scatter_k(const float* __restrict__ feat,
                                                 const void* __restrict__ ei,
                                                 const int* __restrict__ flag,
                                                 float* __restrict__ agg) {
  int t = blockIdx.x * 256 + threadIdx.x;
  int e = t >> 5;
  int f = (t & 31) << 2;
  int is64 = *flag;
  int s = ld_idx(ei, is64, e);
  int d = ld_idx(ei, is64, (long long)NE + e);
  const float4 v = *reinterpret_cast<const float4*>(feat + (size_t)s * DD + f);
  float* a = agg + (size_t)d * DD + f;
  atomicAdd(a + 0, v.x);
  atomicAdd(a + 1, v.y);
  atomicAdd(a + 2, v.z);
  atomicAdd(a + 3, v.w);
}

// ---------------------------------------------------------------------------
// Layer 1: h1 = relu( (agg/max(cnt,1)) @ Wl + bl + x @ Wr )
// Block = 256 threads = 8 nodes x 32 threads; each thread produces 4 output
// features (float4). Node rows staged in LDS (broadcast reads); weight rows
// read coalesced from L1/L2 (128 KB working set, shared by all blocks).
// ---------------------------------------------------------------------------
__global__ __launch_bounds__(256) void sage_l1(
    const float* __restrict__ x, const float* __restrict__ agg,
    const float* __restrict__ cnt, const float* __restrict__ Wl,
    const float* __restrict__ bl, const float* __restrict__ Wr,
    float* __restrict__ h1) {
  __shared__ float sm[8][DD];
  __shared__ float sx[8][DD];
  int tid = threadIdx.x;
  int nb = blockIdx.x * 8;
  for (int i = tid; i < 8 * DD; i += 256) {
    int n = i >> 7, k = i & 127;
    int node = nb + n;
    float inv = 1.0f / fmaxf(cnt[node], 1.0f);
    sm[n][k] = agg[(size_t)node * DD + k] * inv;
    sx[n][k] = x[(size_t)node * DD + k];
  }
  __syncthreads();
  int n = tid >> 5;
  int f = (tid & 31) << 2;
  float4 acc = make_float4(0.f, 0.f, 0.f, 0.f);
#pragma unroll 4
  for (int k = 0; k < DD; ++k) {
    float mk = sm[n][k], xk = sx[n][k];
    float4 wl = *reinterpret_cast<const float4*>(Wl + k * DD + f);
    float4 wr = *reinterpret_cast<const float4*>(Wr + k * DD + f);
    acc.x += mk * wl.x + xk * wr.x;
    acc.y += mk * wl.y + xk * wr.y;
    acc.z += mk * wl.z + xk * wr.z;
    acc.w += mk * wl.w + xk * wr.w;
  }
  float4 b = *reinterpret_cast<const float4*>(bl + f);
  float4 o;
  o.x = fmaxf(acc.x + b.x, 0.f);
  o.y = fmaxf(acc.y + b.y, 0.f);
  o.z = fmaxf(acc.z + b.z, 0.f);
  o.w = fmaxf(acc.w + b.w, 0.f);
  *reinterpret_cast<float4*>(h1 + (size_t)(nb + n) * DD + f) = o;
}

// ---------------------------------------------------------------------------
// Layer 2 + edge-scorer projection, fused. h2 is never materialized:
//   h2 = (agg/max(cnt,1)) @ Wl2 + bl2 + h1 @ Wr2        (no relu)
//   s1[i] = h2[i] . We[0:128],  s2[i] = h2[i] . We[128:256]
// Reduction over the node's 32 threads via width-32 shuffles.
// ---------------------------------------------------------------------------
__global__ __launch_bounds__(256) void sage_l2(
    const float* __restrict__ h1, const float* __restrict__ agg,
    const float* __restrict__ cnt, const float* __restrict__ Wl,
    const float* __restrict__ bl, const float* __restrict__ Wr,
    const float* __restrict__ We, float* __restrict__ s1,
    float* __restrict__ s2) {
  __shared__ float sm[8][DD];
  __shared__ float sh[8][DD];
  int tid = threadIdx.x;
  int nb = blockIdx.x * 8;
  for (int i = tid; i < 8 * DD; i += 256) {
    int n = i >> 7, k = i & 127;
    int node = nb + n;
    float inv = 1.0f / fmaxf(cnt[node], 1.0f);
    sm[n][k] = agg[(size_t)node * DD + k] * inv;
    sh[n][k] = h1[(size_t)node * DD + k];
  }
  __syncthreads();
  int n = tid >> 5;
  int f = (tid & 31) << 2;
  float4 acc = make_float4(0.f, 0.f, 0.f, 0.f);
#pragma unroll 4
  for (int k = 0; k < DD; ++k) {
    float mk = sm[n][k], hk = sh[n][k];
    float4 wl = *reinterpret_cast<const float4*>(Wl + k * DD + f);
    float4 wr = *reinterpret_cast<const float4*>(Wr + k * DD + f);
    acc.x += mk * wl.x + hk * wr.x;
    acc.y += mk * wl.y + hk * wr.y;
    acc.z += mk * wl.z + hk * wr.z;
    acc.w += mk * wl.w + hk * wr.w;
  }
  float4 b = *reinterpret_cast<const float4*>(bl + f);
  float4 h2;
  h2.x = acc.x + b.x;
  h2.y = acc.y + b.y;
  h2.z = acc.z + b.z;
  h2.w = acc.w + b.w;
  float4 w1 = *reinterpret_cast<const float4*>(We + f);
  float4 w2 = *reinterpret_cast<const float4*>(We + DD + f);
  float loc1 = h2.x * w1.x + h2.y * w1.y + h2.z * w1.z + h2.w * w1.w;
  float loc2 = h2.x * w2.x + h2.y * w2.y + h2.z * w2.z + h2.w * w2.w;
  for (int off = 16; off > 0; off >>= 1) {
    loc1 += __shfl_down(loc1, off, 32);
    loc2 += __shfl_down(loc2, off, 32);
  }
  if ((tid & 31) == 0) {
    s1[nb + n] = loc1;
    s2[nb + n] = loc2;
  }
}

// ---------------------------------------------------------------------------
// Edge scores: y[e] = sigmoid(s1[src[e]] + s2[tgt[e]] + b_e)
// ---------------------------------------------------------------------------
__global__ __launch_bounds__(256) void edge_k(const void* __restrict__ ei,
                                              const int* __restrict__ flag,
                                              const float* __restrict__ s1,
                                              const float* __restrict__ s2,
                                              const float* __restrict__ be,
                                              float* __restrict__ out) {
  int e = blockIdx.x * 256 + threadIdx.x;
  int is64 = *flag;
  int s = ld_idx(ei, is64, e);
  int d = ld_idx(ei, is64, (long long)NE + e);
  float v = s1[s] + s2[d] + be[0];
  out[e] = 1.0f / (1.0f + __expf(-v));
}

extern "C" void kernel_launch(void* const* d_in, const int* in_sizes, int n_in,
                              void* d_out, int out_size, void* d_ws, size_t ws_size,
                              hipStream_t stream) {
  const float* x   = (const float*)d_in[0];
  const void*  ei  = d_in[1];
  const float* Wl1 = (const float*)d_in[2];
  const float* bl1 = (const float*)d_in[3];
  const float* Wr1 = (const float*)d_in[4];
  const float* Wl2 = (const float*)d_in[5];
  const float* bl2 = (const float*)d_in[6];
  const float* Wr2 = (const float*)d_in[7];
  const float* We  = (const float*)d_in[8];
  const float* be  = (const float*)d_in[9];
  float* out = (float*)d_out;

  // Workspace layout (floats): cnt[NN] | agg[NN*DD] | h1[NN*DD] | s1[NN] |
  // s2[NN] | flag   (~51.8 MB total)
  float* cnt = (float*)d_ws;
  float* agg = cnt + NN;
  float* h1  = agg + (size_t)NN * DD;
  float* s1  = h1 + (size_t)NN * DD;
  float* s2  = s1 + NN;
  int* flag  = (int*)(s2 + NN);

  detect_k<<<1, 64, 0, stream>>>(ei, flag);
  hipMemsetAsync(cnt, 0, NN * sizeof(float), stream);
  hipMemsetAsync(agg, 0, (size_t)NN * DD * sizeof(float), stream);

  count_k<<<NE / 256, 256, 0, stream>>>(ei, flag, cnt);
  scatter_k<<<(NE * 32) / 256, 256, 0, stream>>>(x, ei, flag, agg);
  sage_l1<<<NN / 8, 256, 0, stream>>>(x, agg, cnt, Wl1, bl1, Wr1, h1);

  hipMemsetAsync(agg, 0, (size_t)NN * DD * sizeof(float), stream);
  scatter_k<<<(NE * 32) / 256, 256, 0, stream>>>(h1, ei, flag, agg);
  sage_l2<<<NN / 8, 256, 0, stream>>>(h1, agg, cnt, Wl2, bl2, Wr2, We, s1, s2);

  edge_k<<<NE / 256, 256, 0, stream>>>(ei, flag, s1, s2, be, out);
}

// Round 2
// 804.109 us; speedup vs baseline: 3.9746x; 3.9746x over previous
//
#include <hip/hip_runtime.h>

#define NN 50000
#define NE 800000
#define DD 128
#define SCAN_T 1024
#define CHUNK 49  // ceil(NN / SCAN_T)

// ---------------------------------------------------------------------------
// Index width detection (reference says int64; harness may deliver int32).
// int32 pairs read as u64 give values >= 2^32 within the first 64 entries.
// ---------------------------------------------------------------------------
__global__ void detect_k(const void* __restrict__ ei, int* __restrict__ flag) {
  if (threadIdx.x == 0 && blockIdx.x == 0) {
    const unsigned long long* p = (const unsigned long long*)ei;
    int is64 = 1;
    for (int i = 0; i < 64; ++i)
      if (p[i] >= (1ull << 32)) { is64 = 0; break; }
    *flag = is64;
  }
}

__device__ __forceinline__ int ld_idx(const void* ei, int is64, long long i) {
  return is64 ? (int)((const long long*)ei)[i] : ((const int*)ei)[i];
}

// ---------------------------------------------------------------------------
// Degree count: deg[tgt[e]] += 1 (int atomics into 200 KB, L2-resident)
// ---------------------------------------------------------------------------
__global__ __launch_bounds__(256) void count_k(const void* __restrict__ ei,
                                               const int* __restrict__ flag,
                                               int* __restrict__ deg) {
  int e = blockIdx.x * 256 + threadIdx.x;
  int is64 = *flag;
  int d = ld_idx(ei, is64, (long long)NE + e);
  atomicAdd(&deg[d], 1);
}

// ---------------------------------------------------------------------------
// Single-block exclusive scan of deg[NN] -> offsets[NN+1]; also seeds cursor.
// ---------------------------------------------------------------------------
__global__ __launch_bounds__(SCAN_T) void scan_k(const int* __restrict__ deg,
                                                 int* __restrict__ offsets,
                                                 int* __restrict__ cursor) {
  __shared__ int sdata[SCAN_T];
  int t = threadIdx.x;
  int base = t * CHUNK;
  int sum = 0;
#pragma unroll
  for (int i = 0; i < CHUNK; ++i) {
    int idx = base + i;
    if (idx < NN) sum += deg[idx];
  }
  sdata[t] = sum;
  __syncthreads();
  for (int off = 1; off < SCAN_T; off <<= 1) {
    int v = (t >= off) ? sdata[t - off] : 0;
    __syncthreads();
    sdata[t] += v;
    __syncthreads();
  }
  int run = sdata[t] - sum;  // exclusive start of this chunk
#pragma unroll
  for (int i = 0; i < CHUNK; ++i) {
    int idx = base + i;
    if (idx < NN) {
      offsets[idx] = run;
      cursor[idx] = run;
      run += deg[idx];
    }
  }
  if (t == 0) offsets[NN] = NE;
}

// ---------------------------------------------------------------------------
// CSR fill: srclist[cursor[tgt[e]]++] = src[e]
// ---------------------------------------------------------------------------
__global__ __launch_bounds__(256) void fill_k(const void* __restrict__ ei,
                                              const int* __restrict__ flag,
                                              int* __restrict__ cursor,
                                              int* __restrict__ srclist) {
  int e = blockIdx.x * 256 + threadIdx.x;
  int is64 = *flag;
  int s = ld_idx(ei, is64, e);
  int d = ld_idx(ei, is64, (long long)NE + e);
  int pos = atomicAdd(&cursor[d], 1);
  srclist[pos] = s;
}

// ---------------------------------------------------------------------------
// Gather-mean: mean[n][:] = (1/max(deg,1)) * sum_{j in N(n)} feat[j][:]
// 32 lanes per node, float4 per lane; one coalesced 512 B row read per edge.
// Writes each destination row exactly once (no atomics).
// ---------------------------------------------------------------------------
__global__ __launch_bounds__(256) void agg_k(const float* __restrict__ feat,
                                             const int* __restrict__ srclist,
                                             const int* __restrict__ offsets,
                                             float* __restrict__ mean) {
  int t = blockIdx.x * 256 + threadIdx.x;
  int node = t >> 5;
  int f = (t & 31) << 2;
  int beg = offsets[node];
  int end = offsets[node + 1];
  float4 acc = make_float4(0.f, 0.f, 0.f, 0.f);
  for (int j = beg; j < end; ++j) {
    int s = srclist[j];  // broadcast across the 32-lane group
    float4 v = *reinterpret_cast<const float4*>(feat + (size_t)s * DD + f);
    acc.x += v.x; acc.y += v.y; acc.z += v.z; acc.w += v.w;
  }
  float inv = 1.0f / fmaxf((float)(end - beg), 1.0f);
  acc.x *= inv; acc.y *= inv; acc.z *= inv; acc.w *= inv;
  *reinterpret_cast<float4*>(mean + (size_t)node * DD + f) = acc;
}

// ---------------------------------------------------------------------------
// Layer 1: h1 = relu( mean @ Wl + bl + x @ Wr )
// 8 nodes/block staged in LDS; 32 lanes x float4 outputs per node.
// ---------------------------------------------------------------------------
__global__ __launch_bounds__(256) void sage_l1(
    const float* __restrict__ x, const float* __restrict__ mean,
    const float* __restrict__ Wl, const float* __restrict__ bl,
    const float* __restrict__ Wr, float* __restrict__ h1) {
  __shared__ float sm[8][DD];
  __shared__ float sx[8][DD];
  int tid = threadIdx.x;
  int nb = blockIdx.x * 8;
  for (int i = tid; i < 8 * DD; i += 256) {
    int n = i >> 7, k = i & 127;
    sm[n][k] = mean[(size_t)(nb + n) * DD + k];
    sx[n][k] = x[(size_t)(nb + n) * DD + k];
  }
  __syncthreads();
  int n = tid >> 5;
  int f = (tid & 31) << 2;
  float4 acc = make_float4(0.f, 0.f, 0.f, 0.f);
#pragma unroll 4
  for (int k = 0; k < DD; ++k) {
    float mk = sm[n][k], xk = sx[n][k];
    float4 wl = *reinterpret_cast<const float4*>(Wl + k * DD + f);
    float4 wr = *reinterpret_cast<const float4*>(Wr + k * DD + f);
    acc.x += mk * wl.x + xk * wr.x;
    acc.y += mk * wl.y + xk * wr.y;
    acc.z += mk * wl.z + xk * wr.z;
    acc.w += mk * wl.w + xk * wr.w;
  }
  float4 b = *reinterpret_cast<const float4*>(bl + f);
  float4 o;
  o.x = fmaxf(acc.x + b.x, 0.f);
  o.y = fmaxf(acc.y + b.y, 0.f);
  o.z = fmaxf(acc.z + b.z, 0.f);
  o.w = fmaxf(acc.w + b.w, 0.f);
  *reinterpret_cast<float4*>(h1 + (size_t)(nb + n) * DD + f) = o;
}

// ---------------------------------------------------------------------------
// Layer 2 fused with edge-scorer projection; h2 never materialized.
//   h2 = mean2 @ Wl2 + bl2 + h1 @ Wr2
//   s1[i] = h2[i].We[0:128], s2[i] = h2[i].We[128:256]
// ---------------------------------------------------------------------------
__global__ __launch_bounds__(256) void sage_l2(
    const float* __restrict__ h1, const float* __restrict__ mean,
    const float* __restrict__ Wl, const float* __restrict__ bl,
    const float* __restrict__ Wr, const float* __restrict__ We,
    float* __restrict__ s1, float* __restrict__ s2) {
  __shared__ float sm[8][DD];
  __shared__ float sh[8][DD];
  int tid = threadIdx.x;
  int nb = blockIdx.x * 8;
  for (int i = tid; i < 8 * DD; i += 256) {
    int n = i >> 7, k = i & 127;
    sm[n][k] = mean[(size_t)(nb + n) * DD + k];
    sh[n][k] = h1[(size_t)(nb + n) * DD + k];
  }
  __syncthreads();
  int n = tid >> 5;
  int f = (tid & 31) << 2;
  float4 acc = make_float4(0.f, 0.f, 0.f, 0.f);
#pragma unroll 4
  for (int k = 0; k < DD; ++k) {
    float mk = sm[n][k], hk = sh[n][k];
    float4 wl = *reinterpret_cast<const float4*>(Wl + k * DD + f);
    float4 wr = *reinterpret_cast<const float4*>(Wr + k * DD + f);
    acc.x += mk * wl.x + hk * wr.x;
    acc.y += mk * wl.y + hk * wr.y;
    acc.z += mk * wl.z + hk * wr.z;
    acc.w += mk * wl.w + hk * wr.w;
  }
  float4 b = *reinterpret_cast<const float4*>(bl + f);
  float4 h2;
  h2.x = acc.x + b.x;
  h2.y = acc.y + b.y;
  h2.z = acc.z + b.z;
  h2.w = acc.w + b.w;
  float4 w1 = *reinterpret_cast<const float4*>(We + f);
  float4 w2 = *reinterpret_cast<const float4*>(We + DD + f);
  float loc1 = h2.x * w1.x + h2.y * w1.y + h2.z * w1.z + h2.w * w1.w;
  float loc2 = h2.x * w2.x + h2.y * w2.y + h2.z * w2.z + h2.w * w2.w;
  for (int off = 16; off > 0; off >>= 1) {
    loc1 += __shfl_down(loc1, off, 32);
    loc2 += __shfl_down(loc2, off, 32);
  }
  if ((tid & 31) == 0) {
    s1[nb + n] = loc1;
    s2[nb + n] = loc2;
  }
}

// ---------------------------------------------------------------------------
// Edge scores: y[e] = sigmoid(s1[src[e]] + s2[tgt[e]] + b_e)
// ---------------------------------------------------------------------------
__global__ __launch_bounds__(256) void edge_k(const void* __restrict__ ei,
                                              const int* __restrict__ flag,
                                              const float* __restrict__ s1,
                                              const float* __restrict__ s2,
                                              const float* __restrict__ be,
                                              float* __restrict__ out) {
  int e = blockIdx.x * 256 + threadIdx.x;
  int is64 = *flag;
  int s = ld_idx(ei, is64, e);
  int d = ld_idx(ei, is64, (long long)NE + e);
  float v = s1[s] + s2[d] + be[0];
  out[e] = 1.0f / (1.0f + __expf(-v));
}

extern "C" void kernel_launch(void* const* d_in, const int* in_sizes, int n_in,
                              void* d_out, int out_size, void* d_ws, size_t ws_size,
                              hipStream_t stream) {
  const float* x   = (const float*)d_in[0];
  const void*  ei  = d_in[1];
  const float* Wl1 = (const float*)d_in[2];
  const float* bl1 = (const float*)d_in[3];
  const float* Wr1 = (const float*)d_in[4];
  const float* Wl2 = (const float*)d_in[5];
  const float* bl2 = (const float*)d_in[6];
  const float* Wr2 = (const float*)d_in[7];
  const float* We  = (const float*)d_in[8];
  const float* be  = (const float*)d_in[9];
  float* out = (float*)d_out;

  // Workspace layout (16B-aligned sections):
  // deg[NN] | offsets[50004] | srclist[NE] | mean[NN*DD] | h1[NN*DD] |
  // s1[NN] (overlaid: cursor during CSR build) | s2[NN] | flag
  int* deg     = (int*)d_ws;
  int* offsets = deg + NN;
  int* srclist = offsets + 50004;
  float* mean  = (float*)(srclist + NE);
  float* h1    = mean + (size_t)NN * DD;
  float* s1    = h1 + (size_t)NN * DD;
  float* s2    = s1 + NN;
  int* flag    = (int*)(s2 + NN);
  int* cursor  = (int*)s1;  // dead by the time sage_l2 writes s1

  detect_k<<<1, 64, 0, stream>>>(ei, flag);
  hipMemsetAsync(deg, 0, NN * sizeof(int), stream);

  // --- CSR build (per-call; edge_index is an input) ---
  count_k<<<NE / 256, 256, 0, stream>>>(ei, flag, deg);
  scan_k<<<1, SCAN_T, 0, stream>>>(deg, offsets, cursor);
  fill_k<<<NE / 256, 256, 0, stream>>>(ei, flag, cursor, srclist);

  // --- Layer 1 ---
  agg_k<<<(NN * 32) / 256, 256, 0, stream>>>(x, srclist, offsets, mean);
  sage_l1<<<NN / 8, 256, 0, stream>>>(x, mean, Wl1, bl1, Wr1, h1);

  // --- Layer 2 (+ fused edge projection) ---
  agg_k<<<(NN * 32) / 256, 256, 0, stream>>>(h1, srclist, offsets, mean);
  sage_l2<<<NN / 8, 256, 0, stream>>>(h1, mean, Wl2, bl2, Wr2, We, s1, s2);

  edge_k<<<NE / 256, 256, 0, stream>>>(ei, flag, s1, s2, be, out);
}

// Round 3
// 535.823 us; speedup vs baseline: 5.9647x; 1.5007x over previous
//
#include <hip/hip_runtime.h>

#define NN 50000
#define NE 800000
#define DD 128
#define SCAN_T 1024
#define CHUNK 49   // ceil(NN / SCAN_T)
#define MT 128     // nodes per GEMM block
#define KC 32      // k-chunk
#define APAD 132   // padded node-dim for k-major A tiles (breaks write conflicts)

// ---------------------------------------------------------------------------
// Index width detection (reference says int64; harness may deliver int32).
// ---------------------------------------------------------------------------
__global__ void detect_k(const void* __restrict__ ei, int* __restrict__ flag) {
  if (threadIdx.x == 0 && blockIdx.x == 0) {
    const unsigned long long* p = (const unsigned long long*)ei;
    int is64 = 1;
    for (int i = 0; i < 64; ++i)
      if (p[i] >= (1ull << 32)) { is64 = 0; break; }
    *flag = is64;
  }
}

__device__ __forceinline__ int ld_idx(const void* ei, int is64, long long i) {
  return is64 ? (int)((const long long*)ei)[i] : ((const int*)ei)[i];
}

// ---------------------------------------------------------------------------
// Degree count
// ---------------------------------------------------------------------------
__global__ __launch_bounds__(256) void count_k(const void* __restrict__ ei,
                                               const int* __restrict__ flag,
                                               int* __restrict__ deg) {
  int e = blockIdx.x * 256 + threadIdx.x;
  int is64 = *flag;
  int d = ld_idx(ei, is64, (long long)NE + e);
  atomicAdd(&deg[d], 1);
}

// ---------------------------------------------------------------------------
// Single-block exclusive scan deg -> offsets; seeds cursor.
// ---------------------------------------------------------------------------
__global__ __launch_bounds__(SCAN_T) void scan_k(const int* __restrict__ deg,
                                                 int* __restrict__ offsets,
                                                 int* __restrict__ cursor) {
  __shared__ int sdata[SCAN_T];
  int t = threadIdx.x;
  int base = t * CHUNK;
  int sum = 0;
#pragma unroll
  for (int i = 0; i < CHUNK; ++i) {
    int idx = base + i;
    if (idx < NN) sum += deg[idx];
  }
  sdata[t] = sum;
  __syncthreads();
  for (int off = 1; off < SCAN_T; off <<= 1) {
    int v = (t >= off) ? sdata[t - off] : 0;
    __syncthreads();
    sdata[t] += v;
    __syncthreads();
  }
  int run = sdata[t] - sum;
#pragma unroll
  for (int i = 0; i < CHUNK; ++i) {
    int idx = base + i;
    if (idx < NN) {
      offsets[idx] = run;
      cursor[idx] = run;
      run += deg[idx];
    }
  }
  if (t == 0) offsets[NN] = NE;
}

// ---------------------------------------------------------------------------
// CSR fill
// ---------------------------------------------------------------------------
__global__ __launch_bounds__(256) void fill_k(const void* __restrict__ ei,
                                              const int* __restrict__ flag,
                                              int* __restrict__ cursor,
                                              int* __restrict__ srclist) {
  int e = blockIdx.x * 256 + threadIdx.x;
  int is64 = *flag;
  int s = ld_idx(ei, is64, e);
  int d = ld_idx(ei, is64, (long long)NE + e);
  int pos = atomicAdd(&cursor[d], 1);
  srclist[pos] = s;
}

// ---------------------------------------------------------------------------
// Gather-mean. 32 lanes/node; srclist read coalesced in chunks of 32 then
// broadcast via shuffle (removes per-edge dependent scalar load).
// ---------------------------------------------------------------------------
__global__ __launch_bounds__(256) void agg_k(const float* __restrict__ feat,
                                             const int* __restrict__ srclist,
                                             const int* __restrict__ offsets,
                                             float* __restrict__ mean) {
  int t = blockIdx.x * 256 + threadIdx.x;
  int node = t >> 5;
  int lane = t & 31;
  int f = lane << 2;
  int beg = offsets[node];
  int end = offsets[node + 1];
  float4 acc = make_float4(0.f, 0.f, 0.f, 0.f);
  for (int c = beg; c < end; c += 32) {
    int idx = c + lane;
    int sl = (idx < end) ? srclist[idx] : 0;
    int m = min(32, end - c);
    for (int jj = 0; jj < m; ++jj) {
      int s = __shfl(sl, jj, 32);
      float4 v = *reinterpret_cast<const float4*>(feat + (size_t)s * DD + f);
      acc.x += v.x; acc.y += v.y; acc.z += v.z; acc.w += v.w;
    }
  }
  float inv = 1.0f / fmaxf((float)(end - beg), 1.0f);
  acc.x *= inv; acc.y *= inv; acc.z *= inv; acc.w *= inv;
  *reinterpret_cast<float4*>(mean + (size_t)node * DD + f) = acc;
}

__device__ __forceinline__ void fma4(float4& c, float a, const float4& b) {
  c.x += a * b.x; c.y += a * b.y; c.z += a * b.z; c.w += a * b.w;
}

// ---------------------------------------------------------------------------
// Register-blocked dual GEMM core: computes, for a 128-node tile,
//   acc = A0 @ B0 + A1 @ B1   (A k-major in LDS, B row-major in LDS)
// Thread (tn=tid&15, tm=tid>>4) owns rows tm*8..+7, cols {tn*4, 64+tn*4}.
// Per k-step: 8 ds_read_b128 + 128 FMA per lane.
// ---------------------------------------------------------------------------
#define GEMM_CORE(A0PTR, A1PTR, B0PTR, B1PTR)                                  \
  for (int k0 = 0; k0 < DD; k0 += KC) {                                        \
    __syncthreads();                                                           \
    for (int it = 0; it < 4; ++it) {                                           \
      int i = it * 256 + tid; /* 0..1023 */                                    \
      int n = i >> 3, j = i & 7;                                               \
      int node = nb + n; if (node >= NN) node = NN - 1;                        \
      float4 v0 = *reinterpret_cast<const float4*>(A0PTR + (size_t)node * DD + k0 + j * 4); \
      float4 v1 = *reinterpret_cast<const float4*>(A1PTR + (size_t)node * DD + k0 + j * 4); \
      int kk = j * 4;                                                          \
      sA0[(kk + 0) * APAD + n] = v0.x; sA0[(kk + 1) * APAD + n] = v0.y;        \
      sA0[(kk + 2) * APAD + n] = v0.z; sA0[(kk + 3) * APAD + n] = v0.w;        \
      sA1[(kk + 0) * APAD + n] = v1.x; sA1[(kk + 1) * APAD + n] = v1.y;        \
      sA1[(kk + 2) * APAD + n] = v1.z; sA1[(kk + 3) * APAD + n] = v1.w;        \
    }                                                                          \
    for (int it = 0; it < 4; ++it) {                                           \
      int i = it * 256 + tid;                                                  \
      int k = i >> 5, c = (i & 31) * 4;                                        \
      *reinterpret_cast<float4*>(&sB0[k * DD + c]) =                           \
          *reinterpret_cast<const float4*>(B0PTR + (k0 + k) * DD + c);         \
      *reinterpret_cast<float4*>(&sB1[k * DD + c]) =                           \
          *reinterpret_cast<const float4*>(B1PTR + (k0 + k) * DD + c);         \
    }                                                                          \
    __syncthreads();                                                           \
    _Pragma("unroll 4")                                                        \
    for (int k = 0; k < KC; ++k) {                                             \
      float4 a0m = *reinterpret_cast<const float4*>(&sA0[k * APAD + tm * 8]);  \
      float4 a1m = *reinterpret_cast<const float4*>(&sA0[k * APAD + tm * 8 + 4]); \
      float4 a0x = *reinterpret_cast<const float4*>(&sA1[k * APAD + tm * 8]);  \
      float4 a1x = *reinterpret_cast<const float4*>(&sA1[k * APAD + tm * 8 + 4]); \
      float4 b0l = *reinterpret_cast<const float4*>(&sB0[k * DD + tn * 4]);    \
      float4 b1l = *reinterpret_cast<const float4*>(&sB0[k * DD + 64 + tn * 4]); \
      float4 b0r = *reinterpret_cast<const float4*>(&sB1[k * DD + tn * 4]);    \
      float4 b1r = *reinterpret_cast<const float4*>(&sB1[k * DD + 64 + tn * 4]); \
      float am[8] = {a0m.x, a0m.y, a0m.z, a0m.w, a1m.x, a1m.y, a1m.z, a1m.w};  \
      float ax[8] = {a0x.x, a0x.y, a0x.z, a0x.w, a1x.x, a1x.y, a1x.z, a1x.w};  \
      _Pragma("unroll")                                                        \
      for (int r = 0; r < 8; ++r) {                                            \
        fma4(acc[r][0], am[r], b0l); fma4(acc[r][0], ax[r], b0r);              \
        fma4(acc[r][1], am[r], b1l); fma4(acc[r][1], ax[r], b1r);              \
      }                                                                        \
    }                                                                          \
  }

// ---------------------------------------------------------------------------
// Layer 1: h1 = relu(mean @ Wl + bl + x @ Wr)
// ---------------------------------------------------------------------------
__global__ __launch_bounds__(256, 2) void sage_l1(
    const float* __restrict__ x, const float* __restrict__ mean,
    const float* __restrict__ Wl, const float* __restrict__ bl,
    const float* __restrict__ Wr, float* __restrict__ h1) {
  __shared__ float sA0[KC * APAD];
  __shared__ float sA1[KC * APAD];
  __shared__ float sB0[KC * DD];
  __shared__ float sB1[KC * DD];
  int tid = threadIdx.x;
  int tn = tid & 15, tm = tid >> 4;
  int nb = blockIdx.x * MT;
  float4 acc[8][2];
#pragma unroll
  for (int r = 0; r < 8; ++r) {
    acc[r][0] = make_float4(0.f, 0.f, 0.f, 0.f);
    acc[r][1] = make_float4(0.f, 0.f, 0.f, 0.f);
  }
  GEMM_CORE(mean, x, Wl, Wr)
  float4 bb0 = *reinterpret_cast<const float4*>(bl + tn * 4);
  float4 bb1 = *reinterpret_cast<const float4*>(bl + 64 + tn * 4);
#pragma unroll
  for (int r = 0; r < 8; ++r) {
    int row = nb + tm * 8 + r;
    if (row < NN) {
      float4 o0, o1;
      o0.x = fmaxf(acc[r][0].x + bb0.x, 0.f);
      o0.y = fmaxf(acc[r][0].y + bb0.y, 0.f);
      o0.z = fmaxf(acc[r][0].z + bb0.z, 0.f);
      o0.w = fmaxf(acc[r][0].w + bb0.w, 0.f);
      o1.x = fmaxf(acc[r][1].x + bb1.x, 0.f);
      o1.y = fmaxf(acc[r][1].y + bb1.y, 0.f);
      o1.z = fmaxf(acc[r][1].z + bb1.z, 0.f);
      o1.w = fmaxf(acc[r][1].w + bb1.w, 0.f);
      *reinterpret_cast<float4*>(h1 + (size_t)row * DD + tn * 4) = o0;
      *reinterpret_cast<float4*>(h1 + (size_t)row * DD + 64 + tn * 4) = o1;
    }
  }
}

// ---------------------------------------------------------------------------
// Layer 2 + fused edge projection: h2 never materialized.
//   h2 = mean2 @ Wl2 + bl2 + h1 @ Wr2
//   s1[i] = h2[i].We[0:128], s2[i] = h2[i].We[128:256]
// ---------------------------------------------------------------------------
__global__ __launch_bounds__(256, 2) void sage_l2(
    const float* __restrict__ h1, const float* __restrict__ mean,
    const float* __restrict__ Wl, const float* __restrict__ bl,
    const float* __restrict__ Wr, const float* __restrict__ We,
    float* __restrict__ s1, float* __restrict__ s2) {
  __shared__ float sA0[KC * APAD];
  __shared__ float sA1[KC * APAD];
  __shared__ float sB0[KC * DD];
  __shared__ float sB1[KC * DD];
  int tid = threadIdx.x;
  int tn = tid & 15, tm = tid >> 4;
  int nb = blockIdx.x * MT;
  float4 acc[8][2];
#pragma unroll
  for (int r = 0; r < 8; ++r) {
    acc[r][0] = make_float4(0.f, 0.f, 0.f, 0.f);
    acc[r][1] = make_float4(0.f, 0.f, 0.f, 0.f);
  }
  GEMM_CORE(mean, h1, Wl, Wr)
  float4 bb0 = *reinterpret_cast<const float4*>(bl + tn * 4);
  float4 bb1 = *reinterpret_cast<const float4*>(bl + 64 + tn * 4);
  float4 w1a = *reinterpret_cast<const float4*>(We + tn * 4);
  float4 w1b = *reinterpret_cast<const float4*>(We + 64 + tn * 4);
  float4 w2a = *reinterpret_cast<const float4*>(We + DD + tn * 4);
  float4 w2b = *reinterpret_cast<const float4*>(We + DD + 64 + tn * 4);
#pragma unroll
  for (int r = 0; r < 8; ++r) {
    float4 h0, h2;
    h0.x = acc[r][0].x + bb0.x; h0.y = acc[r][0].y + bb0.y;
    h0.z = acc[r][0].z + bb0.z; h0.w = acc[r][0].w + bb0.w;
    h2.x = acc[r][1].x + bb1.x; h2.y = acc[r][1].y + bb1.y;
    h2.z = acc[r][1].z + bb1.z; h2.w = acc[r][1].w + bb1.w;
    float v1 = h0.x * w1a.x + h0.y * w1a.y + h0.z * w1a.z + h0.w * w1a.w +
               h2.x * w1b.x + h2.y * w1b.y + h2.z * w1b.z + h2.w * w1b.w;
    float v2 = h0.x * w2a.x + h0.y * w2a.y + h0.z * w2a.z + h0.w * w2a.w +
               h2.x * w2b.x + h2.y * w2b.y + h2.z * w2b.z + h2.w * w2b.w;
    for (int off = 8; off > 0; off >>= 1) {
      v1 += __shfl_down(v1, off, 16);
      v2 += __shfl_down(v2, off, 16);
    }
    int row = nb + tm * 8 + r;
    if (tn == 0 && row < NN) {
      s1[row] = v1;
      s2[row] = v2;
    }
  }
}

// ---------------------------------------------------------------------------
// Edge scores
// ---------------------------------------------------------------------------
__global__ __launch_bounds__(256) void edge_k(const void* __restrict__ ei,
                                              const int* __restrict__ flag,
                                              const float* __restrict__ s1,
                                              const float* __restrict__ s2,
                                              const float* __restrict__ be,
                                              float* __restrict__ out) {
  int e = blockIdx.x * 256 + threadIdx.x;
  int is64 = *flag;
  int s = ld_idx(ei, is64, e);
  int d = ld_idx(ei, is64, (long long)NE + e);
  float v = s1[s] + s2[d] + be[0];
  out[e] = 1.0f / (1.0f + __expf(-v));
}

extern "C" void kernel_launch(void* const* d_in, const int* in_sizes, int n_in,
                              void* d_out, int out_size, void* d_ws, size_t ws_size,
                              hipStream_t stream) {
  const float* x   = (const float*)d_in[0];
  const void*  ei  = d_in[1];
  const float* Wl1 = (const float*)d_in[2];
  const float* bl1 = (const float*)d_in[3];
  const float* Wr1 = (const float*)d_in[4];
  const float* Wl2 = (const float*)d_in[5];
  const float* bl2 = (const float*)d_in[6];
  const float* Wr2 = (const float*)d_in[7];
  const float* We  = (const float*)d_in[8];
  const float* be  = (const float*)d_in[9];
  float* out = (float*)d_out;

  int* deg     = (int*)d_ws;
  int* offsets = deg + NN;
  int* srclist = offsets + 50004;
  float* mean  = (float*)(srclist + NE);
  float* h1    = mean + (size_t)NN * DD;
  float* s1    = h1 + (size_t)NN * DD;
  float* s2    = s1 + NN;
  int* flag    = (int*)(s2 + NN);
  int* cursor  = (int*)s1;  // dead before sage_l2 writes s1

  detect_k<<<1, 64, 0, stream>>>(ei, flag);
  hipMemsetAsync(deg, 0, NN * sizeof(int), stream);

  count_k<<<NE / 256, 256, 0, stream>>>(ei, flag, deg);
  scan_k<<<1, SCAN_T, 0, stream>>>(deg, offsets, cursor);
  fill_k<<<NE / 256, 256, 0, stream>>>(ei, flag, cursor, srclist);

  int gemm_blocks = (NN + MT - 1) / MT;  // 391
  agg_k<<<(NN * 32) / 256, 256, 0, stream>>>(x, srclist, offsets, mean);
  sage_l1<<<gemm_blocks, 256, 0, stream>>>(x, mean, Wl1, bl1, Wr1, h1);

  agg_k<<<(NN * 32) / 256, 256, 0, stream>>>(h1, srclist, offsets, mean);
  sage_l2<<<gemm_blocks, 256, 0, stream>>>(h1, mean, Wl2, bl2, Wr2, We, s1, s2);

  edge_k<<<NE / 256, 256, 0, stream>>>(ei, flag, s1, s2, be, out);
}

// Round 4
// 421.699 us; speedup vs baseline: 7.5789x; 1.2706x over previous
//
#include <hip/hip_runtime.h>

#define NN 50000
#define NE 800000
#define DD 128
#define SB 196     // scan blocks = ceil(NN/256)
#define MT 128     // nodes per GEMM block
#define KC 32      // k-chunk
#define APAD 132   // padded node-dim for k-major A tiles

// ---------------------------------------------------------------------------
// Index width detection (reference says int64; harness may deliver int32).
// ---------------------------------------------------------------------------
__global__ void detect_k(const void* __restrict__ ei, int* __restrict__ flag) {
  if (threadIdx.x == 0 && blockIdx.x == 0) {
    const unsigned long long* p = (const unsigned long long*)ei;
    int is64 = 1;
    for (int i = 0; i < 64; ++i)
      if (p[i] >= (1ull << 32)) { is64 = 0; break; }
    *flag = is64;
  }
}

__device__ __forceinline__ int ld_idx(const void* ei, int is64, long long i) {
  return is64 ? (int)((const long long*)ei)[i] : ((const int*)ei)[i];
}

// ---------------------------------------------------------------------------
// Degree count
// ---------------------------------------------------------------------------
__global__ __launch_bounds__(256) void count_k(const void* __restrict__ ei,
                                               const int* __restrict__ flag,
                                               int* __restrict__ deg) {
  int e = blockIdx.x * 256 + threadIdx.x;
  int is64 = *flag;
  int d = ld_idx(ei, is64, (long long)NE + e);
  atomicAdd(&deg[d], 1);
}

// ---------------------------------------------------------------------------
// Parallel 3-phase exclusive scan of deg[NN] -> offsets[NN+1] (+cursor seed).
// Phase 1: per-block exclusive scan (wave shuffles + LDS wave-sum combine).
// ---------------------------------------------------------------------------
__device__ __forceinline__ int block_incl_scan(int v, int tid, int* wsum) {
  int lane = tid & 63, wave = tid >> 6;
  int s = v;
#pragma unroll
  for (int off = 1; off < 64; off <<= 1) {
    int u = __shfl_up(s, off, 64);
    if (lane >= off) s += u;
  }
  if (lane == 63) wsum[wave] = s;
  __syncthreads();
  int base = 0;
  if (wave > 0) base += wsum[0];
  if (wave > 1) base += wsum[1];
  if (wave > 2) base += wsum[2];
  return base + s;  // block-wide inclusive
}

__global__ __launch_bounds__(256) void scan1_k(const int* __restrict__ deg,
                                               int* __restrict__ offsets,
                                               int* __restrict__ bsum) {
  __shared__ int wsum[4];
  int tid = threadIdx.x;
  int idx = blockIdx.x * 256 + tid;
  int v = (idx < NN) ? deg[idx] : 0;
  int incl = block_incl_scan(v, tid, wsum);
  if (idx < NN) offsets[idx] = incl - v;  // block-local exclusive
  if (tid == 255) bsum[blockIdx.x] = incl;
}

__global__ __launch_bounds__(256) void scan2_k(int* __restrict__ bsum) {
  __shared__ int wsum[4];
  int tid = threadIdx.x;
  int v = (tid < SB) ? bsum[tid] : 0;
  int incl = block_incl_scan(v, tid, wsum);
  if (tid < SB) bsum[tid] = incl - v;  // exclusive block bases
}

__global__ __launch_bounds__(256) void scan3_k(const int* __restrict__ bsum,
                                               int* __restrict__ offsets,
                                               int* __restrict__ cursor) {
  int idx = blockIdx.x * 256 + threadIdx.x;
  if (idx < NN) {
    int o = offsets[idx] + bsum[blockIdx.x];
    offsets[idx] = o;
    cursor[idx] = o;
  }
  if (idx == 0) offsets[NN] = NE;
}

// ---------------------------------------------------------------------------
// CSR fill
// ---------------------------------------------------------------------------
__global__ __launch_bounds__(256) void fill_k(const void* __restrict__ ei,
                                              const int* __restrict__ flag,
                                              int* __restrict__ cursor,
                                              int* __restrict__ srclist) {
  int e = blockIdx.x * 256 + threadIdx.x;
  int is64 = *flag;
  int s = ld_idx(ei, is64, e);
  int d = ld_idx(ei, is64, (long long)NE + e);
  int pos = atomicAdd(&cursor[d], 1);
  srclist[pos] = s;
}

// ---------------------------------------------------------------------------
// Gather-mean. 32 lanes/node; srclist read coalesced in chunks of 32 then
// broadcast via shuffle.
// ---------------------------------------------------------------------------
__global__ __launch_bounds__(256) void agg_k(const float* __restrict__ feat,
                                             const int* __restrict__ srclist,
                                             const int* __restrict__ offsets,
                                             float* __restrict__ mean) {
  int t = blockIdx.x * 256 + threadIdx.x;
  int node = t >> 5;
  int lane = t & 31;
  int f = lane << 2;
  int beg = offsets[node];
  int end = offsets[node + 1];
  float4 acc = make_float4(0.f, 0.f, 0.f, 0.f);
  for (int c = beg; c < end; c += 32) {
    int idx = c + lane;
    int sl = (idx < end) ? srclist[idx] : 0;
    int m = min(32, end - c);
    for (int jj = 0; jj < m; ++jj) {
      int s = __shfl(sl, jj, 32);
      float4 v = *reinterpret_cast<const float4*>(feat + (size_t)s * DD + f);
      acc.x += v.x; acc.y += v.y; acc.z += v.z; acc.w += v.w;
    }
  }
  float inv = 1.0f / fmaxf((float)(end - beg), 1.0f);
  acc.x *= inv; acc.y *= inv; acc.z *= inv; acc.w *= inv;
  *reinterpret_cast<float4*>(mean + (size_t)node * DD + f) = acc;
}

__device__ __forceinline__ void fma4(float4& c, float a, const float4& b) {
  c.x += a * b.x; c.y += a * b.y; c.z += a * b.z; c.w += a * b.w;
}

// ---------------------------------------------------------------------------
// Register-blocked dual GEMM core (see R3 comments).
// ---------------------------------------------------------------------------
#define GEMM_CORE(A0PTR, A1PTR, B0PTR, B1PTR)                                  \
  for (int k0 = 0; k0 < DD; k0 += KC) {                                        \
    __syncthreads();                                                           \
    for (int it = 0; it < 4; ++it) {                                           \
      int i = it * 256 + tid; /* 0..1023 */                                    \
      int n = i >> 3, j = i & 7;                                               \
      int node = nb + n; if (node >= NN) node = NN - 1;                        \
      float4 v0 = *reinterpret_cast<const float4*>(A0PTR + (size_t)node * DD + k0 + j * 4); \
      float4 v1 = *reinterpret_cast<const float4*>(A1PTR + (size_t)node * DD + k0 + j * 4); \
      int kk = j * 4;                                                          \
      sA0[(kk + 0) * APAD + n] = v0.x; sA0[(kk + 1) * APAD + n] = v0.y;        \
      sA0[(kk + 2) * APAD + n] = v0.z; sA0[(kk + 3) * APAD + n] = v0.w;        \
      sA1[(kk + 0) * APAD + n] = v1.x; sA1[(kk + 1) * APAD + n] = v1.y;        \
      sA1[(kk + 2) * APAD + n] = v1.z; sA1[(kk + 3) * APAD + n] = v1.w;        \
    }                                                                          \
    for (int it = 0; it < 4; ++it) {                                           \
      int i = it * 256 + tid;                                                  \
      int k = i >> 5, c = (i & 31) * 4;                                        \
      *reinterpret_cast<float4*>(&sB0[k * DD + c]) =                           \
          *reinterpret_cast<const float4*>(B0PTR + (k0 + k) * DD + c);         \
      *reinterpret_cast<float4*>(&sB1[k * DD + c]) =                           \
          *reinterpret_cast<const float4*>(B1PTR + (k0 + k) * DD + c);         \
    }                                                                          \
    __syncthreads();                                                           \
    _Pragma("unroll 4")                                                        \
    for (int k = 0; k < KC; ++k) {                                             \
      float4 a0m = *reinterpret_cast<const float4*>(&sA0[k * APAD + tm * 8]);  \
      float4 a1m = *reinterpret_cast<const float4*>(&sA0[k * APAD + tm * 8 + 4]); \
      float4 a0x = *reinterpret_cast<const float4*>(&sA1[k * APAD + tm * 8]);  \
      float4 a1x = *reinterpret_cast<const float4*>(&sA1[k * APAD + tm * 8 + 4]); \
      float4 b0l = *reinterpret_cast<const float4*>(&sB0[k * DD + tn * 4]);    \
      float4 b1l = *reinterpret_cast<const float4*>(&sB0[k * DD + 64 + tn * 4]); \
      float4 b0r = *reinterpret_cast<const float4*>(&sB1[k * DD + tn * 4]);    \
      float4 b1r = *reinterpret_cast<const float4*>(&sB1[k * DD + 64 + tn * 4]); \
      float am[8] = {a0m.x, a0m.y, a0m.z, a0m.w, a1m.x, a1m.y, a1m.z, a1m.w};  \
      float ax[8] = {a0x.x, a0x.y, a0x.z, a0x.w, a1x.x, a1x.y, a1x.z, a1x.w};  \
      _Pragma("unroll")                                                        \
      for (int r = 0; r < 8; ++r) {                                            \
        fma4(acc[r][0], am[r], b0l); fma4(acc[r][0], ax[r], b0r);              \
        fma4(acc[r][1], am[r], b1l); fma4(acc[r][1], ax[r], b1r);              \
      }                                                                        \
    }                                                                          \
  }

// ---------------------------------------------------------------------------
// Layer 1: h1 = relu(mean @ Wl + bl + x @ Wr)
// ---------------------------------------------------------------------------
__global__ __launch_bounds__(256, 2) void sage_l1(
    const float* __restrict__ x, const float* __restrict__ mean,
    const float* __restrict__ Wl, const float* __restrict__ bl,
    const float* __restrict__ Wr, float* __restrict__ h1) {
  __shared__ float sA0[KC * APAD];
  __shared__ float sA1[KC * APAD];
  __shared__ float sB0[KC * DD];
  __shared__ float sB1[KC * DD];
  int tid = threadIdx.x;
  int tn = tid & 15, tm = tid >> 4;
  int nb = blockIdx.x * MT;
  float4 acc[8][2];
#pragma unroll
  for (int r = 0; r < 8; ++r) {
    acc[r][0] = make_float4(0.f, 0.f, 0.f, 0.f);
    acc[r][1] = make_float4(0.f, 0.f, 0.f, 0.f);
  }
  GEMM_CORE(mean, x, Wl, Wr)
  float4 bb0 = *reinterpret_cast<const float4*>(bl + tn * 4);
  float4 bb1 = *reinterpret_cast<const float4*>(bl + 64 + tn * 4);
#pragma unroll
  for (int r = 0; r < 8; ++r) {
    int row = nb + tm * 8 + r;
    if (row < NN) {
      float4 o0, o1;
      o0.x = fmaxf(acc[r][0].x + bb0.x, 0.f);
      o0.y = fmaxf(acc[r][0].y + bb0.y, 0.f);
      o0.z = fmaxf(acc[r][0].z + bb0.z, 0.f);
      o0.w = fmaxf(acc[r][0].w + bb0.w, 0.f);
      o1.x = fmaxf(acc[r][1].x + bb1.x, 0.f);
      o1.y = fmaxf(acc[r][1].y + bb1.y, 0.f);
      o1.z = fmaxf(acc[r][1].z + bb1.z, 0.f);
      o1.w = fmaxf(acc[r][1].w + bb1.w, 0.f);
      *reinterpret_cast<float4*>(h1 + (size_t)row * DD + tn * 4) = o0;
      *reinterpret_cast<float4*>(h1 + (size_t)row * DD + 64 + tn * 4) = o1;
    }
  }
}

// ---------------------------------------------------------------------------
// Layer 2 + fused edge projection: h2 never materialized.
// ---------------------------------------------------------------------------
__global__ __launch_bounds__(256, 2) void sage_l2(
    const float* __restrict__ h1, const float* __restrict__ mean,
    const float* __restrict__ Wl, const float* __restrict__ bl,
    const float* __restrict__ Wr, const float* __restrict__ We,
    float* __restrict__ s1, float* __restrict__ s2) {
  __shared__ float sA0[KC * APAD];
  __shared__ float sA1[KC * APAD];
  __shared__ float sB0[KC * DD];
  __shared__ float sB1[KC * DD];
  int tid = threadIdx.x;
  int tn = tid & 15, tm = tid >> 4;
  int nb = blockIdx.x * MT;
  float4 acc[8][2];
#pragma unroll
  for (int r = 0; r < 8; ++r) {
    acc[r][0] = make_float4(0.f, 0.f, 0.f, 0.f);
    acc[r][1] = make_float4(0.f, 0.f, 0.f, 0.f);
  }
  GEMM_CORE(mean, h1, Wl, Wr)
  float4 bb0 = *reinterpret_cast<const float4*>(bl + tn * 4);
  float4 bb1 = *reinterpret_cast<const float4*>(bl + 64 + tn * 4);
  float4 w1a = *reinterpret_cast<const float4*>(We + tn * 4);
  float4 w1b = *reinterpret_cast<const float4*>(We + 64 + tn * 4);
  float4 w2a = *reinterpret_cast<const float4*>(We + DD + tn * 4);
  float4 w2b = *reinterpret_cast<const float4*>(We + DD + 64 + tn * 4);
#pragma unroll
  for (int r = 0; r < 8; ++r) {
    float4 h0, h2;
    h0.x = acc[r][0].x + bb0.x; h0.y = acc[r][0].y + bb0.y;
    h0.z = acc[r][0].z + bb0.z; h0.w = acc[r][0].w + bb0.w;
    h2.x = acc[r][1].x + bb1.x; h2.y = acc[r][1].y + bb1.y;
    h2.z = acc[r][1].z + bb1.z; h2.w = acc[r][1].w + bb1.w;
    float v1 = h0.x * w1a.x + h0.y * w1a.y + h0.z * w1a.z + h0.w * w1a.w +
               h2.x * w1b.x + h2.y * w1b.y + h2.z * w1b.z + h2.w * w1b.w;
    float v2 = h0.x * w2a.x + h0.y * w2a.y + h0.z * w2a.z + h0.w * w2a.w +
               h2.x * w2b.x + h2.y * w2b.y + h2.z * w2b.z + h2.w * w2b.w;
    for (int off = 8; off > 0; off >>= 1) {
      v1 += __shfl_down(v1, off, 16);
      v2 += __shfl_down(v2, off, 16);
    }
    int row = nb + tm * 8 + r;
    if (tn == 0 && row < NN) {
      s1[row] = v1;
      s2[row] = v2;
    }
  }
}

// ---------------------------------------------------------------------------
// Edge scores
// ---------------------------------------------------------------------------
__global__ __launch_bounds__(256) void edge_k(const void* __restrict__ ei,
                                              const int* __restrict__ flag,
                                              const float* __restrict__ s1,
                                              const float* __restrict__ s2,
                                              const float* __restrict__ be,
                                              float* __restrict__ out) {
  int e = blockIdx.x * 256 + threadIdx.x;
  int is64 = *flag;
  int s = ld_idx(ei, is64, e);
  int d = ld_idx(ei, is64, (long long)NE + e);
  float v = s1[s] + s2[d] + be[0];
  out[e] = 1.0f / (1.0f + __expf(-v));
}

extern "C" void kernel_launch(void* const* d_in, const int* in_sizes, int n_in,
                              void* d_out, int out_size, void* d_ws, size_t ws_size,
                              hipStream_t stream) {
  const float* x   = (const float*)d_in[0];
  const void*  ei  = d_in[1];
  const float* Wl1 = (const float*)d_in[2];
  const float* bl1 = (const float*)d_in[3];
  const float* Wr1 = (const float*)d_in[4];
  const float* Wl2 = (const float*)d_in[5];
  const float* bl2 = (const float*)d_in[6];
  const float* Wr2 = (const float*)d_in[7];
  const float* We  = (const float*)d_in[8];
  const float* be  = (const float*)d_in[9];
  float* out = (float*)d_out;

  int* deg     = (int*)d_ws;
  int* offsets = deg + NN;
  int* srclist = offsets + 50004;
  float* mean  = (float*)(srclist + NE);
  float* h1    = mean + (size_t)NN * DD;
  float* s1    = h1 + (size_t)NN * DD;
  float* s2    = s1 + NN;
  int* flag    = (int*)(s2 + NN);
  int* bsum    = flag + 4;
  int* cursor  = (int*)s1;  // dead before sage_l2 writes s1

  detect_k<<<1, 64, 0, stream>>>(ei, flag);
  hipMemsetAsync(deg, 0, NN * sizeof(int), stream);

  count_k<<<NE / 256, 256, 0, stream>>>(ei, flag, deg);
  scan1_k<<<SB, 256, 0, stream>>>(deg, offsets, bsum);
  scan2_k<<<1, 256, 0, stream>>>(bsum);
  scan3_k<<<SB, 256, 0, stream>>>(bsum, offsets, cursor);
  fill_k<<<NE / 256, 256, 0, stream>>>(ei, flag, cursor, srclist);

  int gemm_blocks = (NN + MT - 1) / MT;  // 391
  agg_k<<<(NN * 32) / 256, 256, 0, stream>>>(x, srclist, offsets, mean);
  sage_l1<<<gemm_blocks, 256, 0, stream>>>(x, mean, Wl1, bl1, Wr1, h1);

  agg_k<<<(NN * 32) / 256, 256, 0, stream>>>(h1, srclist, offsets, mean);
  sage_l2<<<gemm_blocks, 256, 0, stream>>>(h1, mean, Wl2, bl2, Wr2, We, s1, s2);

  edge_k<<<NE / 256, 256, 0, stream>>>(ei, flag, s1, s2, be, out);
}

// Round 5
// 378.078 us; speedup vs baseline: 8.4533x; 1.1154x over previous
//
#include <hip/hip_runtime.h>

#define NN 50000
#define NE 800000
#define DD 128
#define SB 196     // scan blocks = ceil(NN/256)
#define MT 128     // nodes per GEMM block
#define KC 32      // k-chunk
#define APAD 132   // padded node-dim for k-major A tiles

typedef unsigned int uint_t;
typedef unsigned short ush_t;

// bf16 helpers: storage is packed ushort pairs in a uint.
__device__ __forceinline__ float bflo(uint_t u) { return __uint_as_float(u << 16); }
__device__ __forceinline__ float bfhi(uint_t u) { return __uint_as_float(u & 0xffff0000u); }
__device__ __forceinline__ ush_t f2bf(float f) {  // RNE
  uint_t u = __float_as_uint(f);
  u += 0x7fffu + ((u >> 16) & 1u);
  return (ush_t)(u >> 16);
}
__device__ __forceinline__ uint2 pack4(float a, float b, float c, float d) {
  uint2 o;
  o.x = (uint_t)f2bf(a) | ((uint_t)f2bf(b) << 16);
  o.y = (uint_t)f2bf(c) | ((uint_t)f2bf(d) << 16);
  return o;
}

// ---------------------------------------------------------------------------
// Index width detection (reference says int64; harness may deliver int32).
// ---------------------------------------------------------------------------
__global__ void detect_k(const void* __restrict__ ei, int* __restrict__ flag) {
  if (threadIdx.x == 0 && blockIdx.x == 0) {
    const unsigned long long* p = (const unsigned long long*)ei;
    int is64 = 1;
    for (int i = 0; i < 64; ++i)
      if (p[i] >= (1ull << 32)) { is64 = 0; break; }
    *flag = is64;
  }
}

__device__ __forceinline__ int ld_idx(const void* ei, int is64, long long i) {
  return is64 ? (int)((const long long*)ei)[i] : ((const int*)ei)[i];
}

// ---------------------------------------------------------------------------
// Pack fp32 -> bf16 (4 elems/thread)
// ---------------------------------------------------------------------------
__global__ __launch_bounds__(256) void pack_k(const float* __restrict__ src,
                                              ush_t* __restrict__ dst) {
  int i = blockIdx.x * 256 + threadIdx.x;  // i < NN*DD/4
  float4 v = reinterpret_cast<const float4*>(src)[i];
  reinterpret_cast<uint2*>(dst)[i] = pack4(v.x, v.y, v.z, v.w);
}

// ---------------------------------------------------------------------------
// Degree count
// ---------------------------------------------------------------------------
__global__ __launch_bounds__(256) void count_k(const void* __restrict__ ei,
                                               const int* __restrict__ flag,
                                               int* __restrict__ deg) {
  int e = blockIdx.x * 256 + threadIdx.x;
  int is64 = *flag;
  int d = ld_idx(ei, is64, (long long)NE + e);
  atomicAdd(&deg[d], 1);
}

// ---------------------------------------------------------------------------
// Parallel 3-phase exclusive scan deg -> offsets (+cursor seed).
// ---------------------------------------------------------------------------
__device__ __forceinline__ int block_incl_scan(int v, int tid, int* wsum) {
  int lane = tid & 63, wave = tid >> 6;
  int s = v;
#pragma unroll
  for (int off = 1; off < 64; off <<= 1) {
    int u = __shfl_up(s, off, 64);
    if (lane >= off) s += u;
  }
  if (lane == 63) wsum[wave] = s;
  __syncthreads();
  int base = 0;
  if (wave > 0) base += wsum[0];
  if (wave > 1) base += wsum[1];
  if (wave > 2) base += wsum[2];
  return base + s;
}

__global__ __launch_bounds__(256) void scan1_k(const int* __restrict__ deg,
                                               int* __restrict__ offsets,
                                               int* __restrict__ bsum) {
  __shared__ int wsum[4];
  int tid = threadIdx.x;
  int idx = blockIdx.x * 256 + tid;
  int v = (idx < NN) ? deg[idx] : 0;
  int incl = block_incl_scan(v, tid, wsum);
  if (idx < NN) offsets[idx] = incl - v;
  if (tid == 255) bsum[blockIdx.x] = incl;
}

__global__ __launch_bounds__(256) void scan2_k(int* __restrict__ bsum) {
  __shared__ int wsum[4];
  int tid = threadIdx.x;
  int v = (tid < SB) ? bsum[tid] : 0;
  int incl = block_incl_scan(v, tid, wsum);
  if (tid < SB) bsum[tid] = incl - v;
}

__global__ __launch_bounds__(256) void scan3_k(const int* __restrict__ bsum,
                                               int* __restrict__ offsets,
                                               int* __restrict__ cursor) {
  int idx = blockIdx.x * 256 + threadIdx.x;
  if (idx < NN) {
    int o = offsets[idx] + bsum[blockIdx.x];
    offsets[idx] = o;
    cursor[idx] = o;
  }
  if (idx == 0) offsets[NN] = NE;
}

// ---------------------------------------------------------------------------
// CSR fill
// ---------------------------------------------------------------------------
__global__ __launch_bounds__(256) void fill_k(const void* __restrict__ ei,
                                              const int* __restrict__ flag,
                                              int* __restrict__ cursor,
                                              int* __restrict__ srclist) {
  int e = blockIdx.x * 256 + threadIdx.x;
  int is64 = *flag;
  int s = ld_idx(ei, is64, e);
  int d = ld_idx(ei, is64, (long long)NE + e);
  int pos = atomicAdd(&cursor[d], 1);
  srclist[pos] = s;
}

// ---------------------------------------------------------------------------
// Gather-mean over bf16 features: 32 lanes/node, uint2 (4 bf16) per lane.
// Accumulate fp32, write bf16 mean.
// ---------------------------------------------------------------------------
__global__ __launch_bounds__(256) void agg_k(const ush_t* __restrict__ featb,
                                             const int* __restrict__ srclist,
                                             const int* __restrict__ offsets,
                                             ush_t* __restrict__ meanb) {
  int t = blockIdx.x * 256 + threadIdx.x;
  int node = t >> 5;
  int lane = t & 31;
  int f = lane << 2;
  int beg = offsets[node];
  int end = offsets[node + 1];
  float4 acc = make_float4(0.f, 0.f, 0.f, 0.f);
  for (int c = beg; c < end; c += 32) {
    int idx = c + lane;
    int sl = (idx < end) ? srclist[idx] : 0;
    int m = min(32, end - c);
    for (int jj = 0; jj < m; ++jj) {
      int s = __shfl(sl, jj, 32);
      uint2 v = *reinterpret_cast<const uint2*>(featb + (size_t)s * DD + f);
      acc.x += bflo(v.x); acc.y += bfhi(v.x);
      acc.z += bflo(v.y); acc.w += bfhi(v.y);
    }
  }
  float inv = 1.0f / fmaxf((float)(end - beg), 1.0f);
  *reinterpret_cast<uint2*>(meanb + (size_t)node * DD + f) =
      pack4(acc.x * inv, acc.y * inv, acc.z * inv, acc.w * inv);
}

__device__ __forceinline__ void fma4(float4& c, float a, const float4& b) {
  c.x += a * b.x; c.y += a * b.y; c.z += a * b.z; c.w += a * b.w;
}

// ---------------------------------------------------------------------------
// Register-blocked dual GEMM core; A operands bf16 (unpacked into LDS fp32),
// B operands fp32. acc = A0 @ B0 + A1 @ B1 for a 128-node tile.
// ---------------------------------------------------------------------------
#define GEMM_CORE(A0PTR, A1PTR, B0PTR, B1PTR)                                  \
  for (int k0 = 0; k0 < DD; k0 += KC) {                                        \
    __syncthreads();                                                           \
    for (int it = 0; it < 4; ++it) {                                           \
      int i = it * 256 + tid; /* 0..1023 */                                    \
      int n = i >> 3, j = i & 7;                                               \
      int node = nb + n; if (node >= NN) node = NN - 1;                        \
      uint2 u0 = *reinterpret_cast<const uint2*>(A0PTR + (size_t)node * DD + k0 + j * 4); \
      uint2 u1 = *reinterpret_cast<const uint2*>(A1PTR + (size_t)node * DD + k0 + j * 4); \
      int kk = j * 4;                                                          \
      sA0[(kk + 0) * APAD + n] = bflo(u0.x); sA0[(kk + 1) * APAD + n] = bfhi(u0.x); \
      sA0[(kk + 2) * APAD + n] = bflo(u0.y); sA0[(kk + 3) * APAD + n] = bfhi(u0.y); \
      sA1[(kk + 0) * APAD + n] = bflo(u1.x); sA1[(kk + 1) * APAD + n] = bfhi(u1.x); \
      sA1[(kk + 2) * APAD + n] = bflo(u1.y); sA1[(kk + 3) * APAD + n] = bfhi(u1.y); \
    }                                                                          \
    for (int it = 0; it < 4; ++it) {                                           \
      int i = it * 256 + tid;                                                  \
      int k = i >> 5, c = (i & 31) * 4;                                        \
      *reinterpret_cast<float4*>(&sB0[k * DD + c]) =                           \
          *reinterpret_cast<const float4*>(B0PTR + (k0 + k) * DD + c);         \
      *reinterpret_cast<float4*>(&sB1[k * DD + c]) =                           \
          *reinterpret_cast<const float4*>(B1PTR + (k0 + k) * DD + c);         \
    }                                                                          \
    __syncthreads();                                                           \
    _Pragma("unroll 4")                                                        \
    for (int k = 0; k < KC; ++k) {                                             \
      float4 a0m = *reinterpret_cast<const float4*>(&sA0[k * APAD + tm * 8]);  \
      float4 a1m = *reinterpret_cast<const float4*>(&sA0[k * APAD + tm * 8 + 4]); \
      float4 a0x = *reinterpret_cast<const float4*>(&sA1[k * APAD + tm * 8]);  \
      float4 a1x = *reinterpret_cast<const float4*>(&sA1[k * APAD + tm * 8 + 4]); \
      float4 b0l = *reinterpret_cast<const float4*>(&sB0[k * DD + tn * 4]);    \
      float4 b1l = *reinterpret_cast<const float4*>(&sB0[k * DD + 64 + tn * 4]); \
      float4 b0r = *reinterpret_cast<const float4*>(&sB1[k * DD + tn * 4]);    \
      float4 b1r = *reinterpret_cast<const float4*>(&sB1[k * DD + 64 + tn * 4]); \
      float am[8] = {a0m.x, a0m.y, a0m.z, a0m.w, a1m.x, a1m.y, a1m.z, a1m.w};  \
      float ax[8] = {a0x.x, a0x.y, a0x.z, a0x.w, a1x.x, a1x.y, a1x.z, a1x.w};  \
      _Pragma("unroll")                                                        \
      for (int r = 0; r < 8; ++r) {                                            \
        fma4(acc[r][0], am[r], b0l); fma4(acc[r][0], ax[r], b0r);              \
        fma4(acc[r][1], am[r], b1l); fma4(acc[r][1], ax[r], b1r);              \
      }                                                                        \
    }                                                                          \
  }

// ---------------------------------------------------------------------------
// Layer 1: h1 = relu(mean @ Wl + bl + x @ Wr), written as bf16.
// ---------------------------------------------------------------------------
__global__ __launch_bounds__(256, 2) void sage_l1(
    const ush_t* __restrict__ xb, const ush_t* __restrict__ meanb,
    const float* __restrict__ Wl, const float* __restrict__ bl,
    const float* __restrict__ Wr, ush_t* __restrict__ h1b) {
  __shared__ float sA0[KC * APAD];
  __shared__ float sA1[KC * APAD];
  __shared__ float sB0[KC * DD];
  __shared__ float sB1[KC * DD];
  int tid = threadIdx.x;
  int tn = tid & 15, tm = tid >> 4;
  int nb = blockIdx.x * MT;
  float4 acc[8][2];
#pragma unroll
  for (int r = 0; r < 8; ++r) {
    acc[r][0] = make_float4(0.f, 0.f, 0.f, 0.f);
    acc[r][1] = make_float4(0.f, 0.f, 0.f, 0.f);
  }
  GEMM_CORE(meanb, xb, Wl, Wr)
  float4 bb0 = *reinterpret_cast<const float4*>(bl + tn * 4);
  float4 bb1 = *reinterpret_cast<const float4*>(bl + 64 + tn * 4);
#pragma unroll
  for (int r = 0; r < 8; ++r) {
    int row = nb + tm * 8 + r;
    if (row < NN) {
      *reinterpret_cast<uint2*>(h1b + (size_t)row * DD + tn * 4) =
          pack4(fmaxf(acc[r][0].x + bb0.x, 0.f), fmaxf(acc[r][0].y + bb0.y, 0.f),
                fmaxf(acc[r][0].z + bb0.z, 0.f), fmaxf(acc[r][0].w + bb0.w, 0.f));
      *reinterpret_cast<uint2*>(h1b + (size_t)row * DD + 64 + tn * 4) =
          pack4(fmaxf(acc[r][1].x + bb1.x, 0.f), fmaxf(acc[r][1].y + bb1.y, 0.f),
                fmaxf(acc[r][1].z + bb1.z, 0.f), fmaxf(acc[r][1].w + bb1.w, 0.f));
    }
  }
}

// ---------------------------------------------------------------------------
// Layer 2 + fused edge projection: h2 never materialized.
// ---------------------------------------------------------------------------
__global__ __launch_bounds__(256, 2) void sage_l2(
    const ush_t* __restrict__ h1b, const ush_t* __restrict__ meanb,
    const float* __restrict__ Wl, const float* __restrict__ bl,
    const float* __restrict__ Wr, const float* __restrict__ We,
    float* __restrict__ s1, float* __restrict__ s2) {
  __shared__ float sA0[KC * APAD];
  __shared__ float sA1[KC * APAD];
  __shared__ float sB0[KC * DD];
  __shared__ float sB1[KC * DD];
  int tid = threadIdx.x;
  int tn = tid & 15, tm = tid >> 4;
  int nb = blockIdx.x * MT;
  float4 acc[8][2];
#pragma unroll
  for (int r = 0; r < 8; ++r) {
    acc[r][0] = make_float4(0.f, 0.f, 0.f, 0.f);
    acc[r][1] = make_float4(0.f, 0.f, 0.f, 0.f);
  }
  GEMM_CORE(meanb, h1b, Wl, Wr)
  float4 bb0 = *reinterpret_cast<const float4*>(bl + tn * 4);
  float4 bb1 = *reinterpret_cast<const float4*>(bl + 64 + tn * 4);
  float4 w1a = *reinterpret_cast<const float4*>(We + tn * 4);
  float4 w1b = *reinterpret_cast<const float4*>(We + 64 + tn * 4);
  float4 w2a = *reinterpret_cast<const float4*>(We + DD + tn * 4);
  float4 w2b = *reinterpret_cast<const float4*>(We + DD + 64 + tn * 4);
#pragma unroll
  for (int r = 0; r < 8; ++r) {
    float4 h0, h2;
    h0.x = acc[r][0].x + bb0.x; h0.y = acc[r][0].y + bb0.y;
    h0.z = acc[r][0].z + bb0.z; h0.w = acc[r][0].w + bb0.w;
    h2.x = acc[r][1].x + bb1.x; h2.y = acc[r][1].y + bb1.y;
    h2.z = acc[r][1].z + bb1.z; h2.w = acc[r][1].w + bb1.w;
    float v1 = h0.x * w1a.x + h0.y * w1a.y + h0.z * w1a.z + h0.w * w1a.w +
               h2.x * w1b.x + h2.y * w1b.y + h2.z * w1b.z + h2.w * w1b.w;
    float v2 = h0.x * w2a.x + h0.y * w2a.y + h0.z * w2a.z + h0.w * w2a.w +
               h2.x * w2b.x + h2.y * w2b.y + h2.z * w2b.z + h2.w * w2b.w;
    for (int off = 8; off > 0; off >>= 1) {
      v1 += __shfl_down(v1, off, 16);
      v2 += __shfl_down(v2, off, 16);
    }
    int row = nb + tm * 8 + r;
    if (tn == 0 && row < NN) {
      s1[row] = v1;
      s2[row] = v2;
    }
  }
}

// ---------------------------------------------------------------------------
// Edge scores
// ---------------------------------------------------------------------------
__global__ __launch_bounds__(256) void edge_k(const void* __restrict__ ei,
                                              const int* __restrict__ flag,
                                              const float* __restrict__ s1,
                                              const float* __restrict__ s2,
                                              const float* __restrict__ be,
                                              float* __restrict__ out) {
  int e = blockIdx.x * 256 + threadIdx.x;
  int is64 = *flag;
  int s = ld_idx(ei, is64, e);
  int d = ld_idx(ei, is64, (long long)NE + e);
  float v = s1[s] + s2[d] + be[0];
  out[e] = 1.0f / (1.0f + __expf(-v));
}

extern "C" void kernel_launch(void* const* d_in, const int* in_sizes, int n_in,
                              void* d_out, int out_size, void* d_ws, size_t ws_size,
                              hipStream_t stream) {
  const float* x   = (const float*)d_in[0];
  const void*  ei  = d_in[1];
  const float* Wl1 = (const float*)d_in[2];
  const float* bl1 = (const float*)d_in[3];
  const float* Wr1 = (const float*)d_in[4];
  const float* Wl2 = (const float*)d_in[5];
  const float* bl2 = (const float*)d_in[6];
  const float* Wr2 = (const float*)d_in[7];
  const float* We  = (const float*)d_in[8];
  const float* be  = (const float*)d_in[9];
  float* out = (float*)d_out;

  // Workspace (4B units): deg | offsets | srclist | xb | meanb | h1b | s1 |
  // s2 | flag | bsum  (~42 MB, less than the R4 layout)
  int* deg     = (int*)d_ws;
  int* offsets = deg + NN;
  int* srclist = offsets + 50004;
  ush_t* xb    = (ush_t*)(srclist + NE);           // NN*DD bf16 = 3.2M uints
  ush_t* meanb = xb + (size_t)NN * DD;
  ush_t* h1b   = meanb + (size_t)NN * DD;
  float* s1    = (float*)(h1b + (size_t)NN * DD);
  float* s2    = s1 + NN;
  int* flag    = (int*)(s2 + NN);
  int* bsum    = flag + 4;
  int* cursor  = (int*)s1;  // dead before sage_l2 writes s1

  detect_k<<<1, 64, 0, stream>>>(ei, flag);
  hipMemsetAsync(deg, 0, NN * sizeof(int), stream);
  pack_k<<<(NN * DD / 4 + 255) / 256, 256, 0, stream>>>(x, xb);

  count_k<<<NE / 256, 256, 0, stream>>>(ei, flag, deg);
  scan1_k<<<SB, 256, 0, stream>>>(deg, offsets, bsum);
  scan2_k<<<1, 256, 0, stream>>>(bsum);
  scan3_k<<<SB, 256, 0, stream>>>(bsum, offsets, cursor);
  fill_k<<<NE / 256, 256, 0, stream>>>(ei, flag, cursor, srclist);

  int gemm_blocks = (NN + MT - 1) / MT;  // 391
  agg_k<<<(NN * 32) / 256, 256, 0, stream>>>(xb, srclist, offsets, meanb);
  sage_l1<<<gemm_blocks, 256, 0, stream>>>(xb, meanb, Wl1, bl1, Wr1, h1b);

  agg_k<<<(NN * 32) / 256, 256, 0, stream>>>(h1b, srclist, offsets, meanb);
  sage_l2<<<gemm_blocks, 256, 0, stream>>>(h1b, meanb, Wl2, bl2, Wr2, We, s1, s2);

  edge_k<<<NE / 256, 256, 0, stream>>>(ei, flag, s1, s2, be, out);
}

// Round 6
// 308.716 us; speedup vs baseline: 10.3526x; 1.2247x over previous
//
#include <hip/hip_runtime.h>

#define NN 50000
#define NE 800000
#define DD 128
#define SB 196     // scan blocks = ceil(NN/256)
#define BPAD 264   // ushorts per col in LDS B (256 + 8 pad -> dword stride 132)

typedef unsigned int uint_t;
typedef unsigned short ush_t;
typedef __attribute__((ext_vector_type(8))) short short8;   // 8 bf16 (4 VGPRs)
typedef __attribute__((ext_vector_type(4))) float f32x4;    // MFMA C/D

// bf16 helpers
__device__ __forceinline__ float bflo(uint_t u) { return __uint_as_float(u << 16); }
__device__ __forceinline__ float bfhi(uint_t u) { return __uint_as_float(u & 0xffff0000u); }
__device__ __forceinline__ ush_t f2bf(float f) {  // RNE
  uint_t u = __float_as_uint(f);
  u += 0x7fffu + ((u >> 16) & 1u);
  return (ush_t)(u >> 16);
}
__device__ __forceinline__ uint2 pack4(float a, float b, float c, float d) {
  uint2 o;
  o.x = (uint_t)f2bf(a) | ((uint_t)f2bf(b) << 16);
  o.y = (uint_t)f2bf(c) | ((uint_t)f2bf(d) << 16);
  return o;
}

// ---------------------------------------------------------------------------
// Index width detection (reference says int64; harness may deliver int32).
// ---------------------------------------------------------------------------
__global__ void detect_k(const void* __restrict__ ei, int* __restrict__ flag) {
  if (threadIdx.x == 0 && blockIdx.x == 0) {
    const unsigned long long* p = (const unsigned long long*)ei;
    int is64 = 1;
    for (int i = 0; i < 64; ++i)
      if (p[i] >= (1ull << 32)) { is64 = 0; break; }
    *flag = is64;
  }
}

__device__ __forceinline__ int ld_idx(const void* ei, int is64, long long i) {
  return is64 ? (int)((const long long*)ei)[i] : ((const int*)ei)[i];
}

// ---------------------------------------------------------------------------
// Pack fp32 -> bf16 (4 elems/thread), for x.
// ---------------------------------------------------------------------------
__global__ __launch_bounds__(256) void pack_k(const float* __restrict__ src,
                                              ush_t* __restrict__ dst) {
  int i = blockIdx.x * 256 + threadIdx.x;
  float4 v = reinterpret_cast<const float4*>(src)[i];
  reinterpret_cast<uint2*>(dst)[i] = pack4(v.x, v.y, v.z, v.w);
}

// ---------------------------------------------------------------------------
// Weight prep: Wt[layer][col][k] bf16, K=256 combined: k<128 -> Wl[k][col],
// k>=128 -> Wr[k-128][col]. One element per thread, read-coalesced-ish.
// ---------------------------------------------------------------------------
__global__ __launch_bounds__(256) void wprep_k(
    const float* __restrict__ Wl1, const float* __restrict__ Wr1,
    const float* __restrict__ Wl2, const float* __restrict__ Wr2,
    ush_t* __restrict__ Wt1, ush_t* __restrict__ Wt2) {
  int e = blockIdx.x * 256 + threadIdx.x;  // < 65536
  int layer = e >> 15;
  int r = e & 32767;
  int col = r >> 8;
  int k = r & 255;
  const float* Wl = layer ? Wl2 : Wl1;
  const float* Wr = layer ? Wr2 : Wr1;
  float v = (k < DD) ? Wl[k * DD + col] : Wr[(k - DD) * DD + col];
  ush_t* Wt = layer ? Wt2 : Wt1;
  Wt[col * 256 + k] = f2bf(v);
}

// ---------------------------------------------------------------------------
// Degree count
// ---------------------------------------------------------------------------
__global__ __launch_bounds__(256) void count_k(const void* __restrict__ ei,
                                               const int* __restrict__ flag,
                                               int* __restrict__ deg) {
  int e = blockIdx.x * 256 + threadIdx.x;
  int is64 = *flag;
  int d = ld_idx(ei, is64, (long long)NE + e);
  atomicAdd(&deg[d], 1);
}

// ---------------------------------------------------------------------------
// Parallel 3-phase exclusive scan deg -> offsets (+cursor seed).
// ---------------------------------------------------------------------------
__device__ __forceinline__ int block_incl_scan(int v, int tid, int* wsum) {
  int lane = tid & 63, wave = tid >> 6;
  int s = v;
#pragma unroll
  for (int off = 1; off < 64; off <<= 1) {
    int u = __shfl_up(s, off, 64);
    if (lane >= off) s += u;
  }
  if (lane == 63) wsum[wave] = s;
  __syncthreads();
  int base = 0;
  if (wave > 0) base += wsum[0];
  if (wave > 1) base += wsum[1];
  if (wave > 2) base += wsum[2];
  return base + s;
}

__global__ __launch_bounds__(256) void scan1_k(const int* __restrict__ deg,
                                               int* __restrict__ offsets,
                                               int* __restrict__ bsum) {
  __shared__ int wsum[4];
  int tid = threadIdx.x;
  int idx = blockIdx.x * 256 + tid;
  int v = (idx < NN) ? deg[idx] : 0;
  int incl = block_incl_scan(v, tid, wsum);
  if (idx < NN) offsets[idx] = incl - v;
  if (tid == 255) bsum[blockIdx.x] = incl;
}

__global__ __launch_bounds__(256) void scan2_k(int* __restrict__ bsum) {
  __shared__ int wsum[4];
  int tid = threadIdx.x;
  int v = (tid < SB) ? bsum[tid] : 0;
  int incl = block_incl_scan(v, tid, wsum);
  if (tid < SB) bsum[tid] = incl - v;
}

__global__ __launch_bounds__(256) void scan3_k(const int* __restrict__ bsum,
                                               int* __restrict__ offsets,
                                               int* __restrict__ cursor) {
  int idx = blockIdx.x * 256 + threadIdx.x;
  if (idx < NN) {
    int o = offsets[idx] + bsum[blockIdx.x];
    offsets[idx] = o;
    cursor[idx] = o;
  }
  if (idx == 0) offsets[NN] = NE;
}

// ---------------------------------------------------------------------------
// CSR fill
// ---------------------------------------------------------------------------
__global__ __launch_bounds__(256) void fill_k(const void* __restrict__ ei,
                                              const int* __restrict__ flag,
                                              int* __restrict__ cursor,
                                              int* __restrict__ srclist) {
  int e = blockIdx.x * 256 + threadIdx.x;
  int is64 = *flag;
  int s = ld_idx(ei, is64, e);
  int d = ld_idx(ei, is64, (long long)NE + e);
  int pos = atomicAdd(&cursor[d], 1);
  srclist[pos] = s;
}

// ---------------------------------------------------------------------------
// Gather-mean over bf16 features.
// ---------------------------------------------------------------------------
__global__ __launch_bounds__(256) void agg_k(const ush_t* __restrict__ featb,
                                             const int* __restrict__ srclist,
                                             const int* __restrict__ offsets,
                                             ush_t* __restrict__ meanb) {
  int t = blockIdx.x * 256 + threadIdx.x;
  int node = t >> 5;
  int lane = t & 31;
  int f = lane << 2;
  int beg = offsets[node];
  int end = offsets[node + 1];
  float4 acc = make_float4(0.f, 0.f, 0.f, 0.f);
  for (int c = beg; c < end; c += 32) {
    int idx = c + lane;
    int sl = (idx < end) ? srclist[idx] : 0;
    int m = min(32, end - c);
    for (int jj = 0; jj < m; ++jj) {
      int s = __shfl(sl, jj, 32);
      uint2 v = *reinterpret_cast<const uint2*>(featb + (size_t)s * DD + f);
      acc.x += bflo(v.x); acc.y += bfhi(v.x);
      acc.z += bflo(v.y); acc.w += bfhi(v.y);
    }
  }
  float inv = 1.0f / fmaxf((float)(end - beg), 1.0f);
  *reinterpret_cast<uint2*>(meanb + (size_t)node * DD + f) =
      pack4(acc.x * inv, acc.y * inv, acc.z * inv, acc.w * inv);
}

// ---------------------------------------------------------------------------
// MFMA GEMM core (shared): block = 256 thr = 4 waves, 64 node-rows/block.
// Wave w computes rows nb+w*16..+15 x 128 cols via 8 tiles of 16x16, K=256
// ([A0||A1] @ Wt). A-frags loaded straight from global bf16
// (A[m=lane&15][k=quad*8+j], one 16B load per K-chunk). B staged in LDS
// transposed with +8 ushort pad (dword stride 132 -> conflict-free b128).
// ---------------------------------------------------------------------------
#define MFMA_CORE(A0PTR, A1PTR, WTPTR)                                         \
  int tid = threadIdx.x;                                                       \
  int lane = tid & 63;                                                         \
  int wave = tid >> 6;                                                         \
  int n15 = lane & 15, quad = lane >> 4;                                       \
  int nb = blockIdx.x * 64;                                                    \
  /* stage Wt into LDS: 4096 chunks of 16B */                                  \
  for (int it = 0; it < 16; ++it) {                                            \
    int i = it * 256 + tid;                                                    \
    int col = i >> 5, c = i & 31;                                              \
    *reinterpret_cast<short8*>(&sB[col * BPAD + c * 8]) =                      \
        reinterpret_cast<const short8*>(WTPTR)[i];                             \
  }                                                                            \
  __syncthreads();                                                             \
  int row = nb + wave * 16 + n15;                                              \
  int arow = (row < NN) ? row : (NN - 1);                                      \
  const ush_t* a0 = A0PTR + (size_t)arow * DD;                                 \
  const ush_t* a1 = A1PTR + (size_t)arow * DD;                                 \
  f32x4 acc[8];                                                                \
  _Pragma("unroll")                                                            \
  for (int t = 0; t < 8; ++t) acc[t] = (f32x4){0.f, 0.f, 0.f, 0.f};           \
  _Pragma("unroll")                                                            \
  for (int c = 0; c < 8; ++c) {                                                \
    const ush_t* ap = (c < 4) ? (a0 + c * 32 + quad * 8)                       \
                              : (a1 + (c - 4) * 32 + quad * 8);                \
    short8 af = *reinterpret_cast<const short8*>(ap);                          \
    int kb = c * 32 + quad * 8;                                                \
    _Pragma("unroll")                                                          \
    for (int t = 0; t < 8; ++t) {                                              \
      short8 bf = *reinterpret_cast<const short8*>(&sB[(t * 16 + n15) * BPAD + kb]); \
      acc[t] = __builtin_amdgcn_mfma_f32_16x16x32_bf16(af, bf, acc[t], 0, 0, 0); \
    }                                                                          \
  }

// ---------------------------------------------------------------------------
// Layer 1: h1 = relu([mean||x] @ Wt1 + bl1), bf16 out.
// C/D layout: col = lane&15 (+16t), row = quad*4 + reg.
// ---------------------------------------------------------------------------
__global__ __launch_bounds__(256, 2) void sage_l1(
    const ush_t* __restrict__ meanb, const ush_t* __restrict__ xb,
    const ush_t* __restrict__ Wt1, const float* __restrict__ bl,
    ush_t* __restrict__ h1b) {
  __shared__ ush_t sB[128 * BPAD];
  MFMA_CORE(meanb, xb, Wt1)
#pragma unroll
  for (int t = 0; t < 8; ++t) {
    int col = t * 16 + n15;
    float b = bl[col];
#pragma unroll
    for (int reg = 0; reg < 4; ++reg) {
      int r = nb + wave * 16 + quad * 4 + reg;
      if (r < NN)
        h1b[(size_t)r * DD + col] = f2bf(fmaxf(acc[t][reg] + b, 0.f));
    }
  }
}

// ---------------------------------------------------------------------------
// Layer 2 + fused edge projection: h2 = [mean||h1] @ Wt2 + bl2 (never stored);
// s1 = h2 . We[0:128], s2 = h2 . We[128:256] via width-16 shuffle reduce.
// ---------------------------------------------------------------------------
__global__ __launch_bounds__(256, 2) void sage_l2(
    const ush_t* __restrict__ meanb, const ush_t* __restrict__ h1b,
    const ush_t* __restrict__ Wt2, const float* __restrict__ bl,
    const float* __restrict__ We, float* __restrict__ s1,
    float* __restrict__ s2) {
  __shared__ ush_t sB[128 * BPAD];
  MFMA_CORE(meanb, h1b, Wt2)
  float p1[4] = {0.f, 0.f, 0.f, 0.f};
  float p2[4] = {0.f, 0.f, 0.f, 0.f};
#pragma unroll
  for (int t = 0; t < 8; ++t) {
    int col = t * 16 + n15;
    float b = bl[col];
    float w1 = We[col];
    float w2 = We[DD + col];
#pragma unroll
    for (int reg = 0; reg < 4; ++reg) {
      float v = acc[t][reg] + b;
      p1[reg] += v * w1;
      p2[reg] += v * w2;
    }
  }
#pragma unroll
  for (int reg = 0; reg < 4; ++reg) {
    float v1 = p1[reg], v2 = p2[reg];
    for (int off = 8; off > 0; off >>= 1) {
      v1 += __shfl_down(v1, off, 16);
      v2 += __shfl_down(v2, off, 16);
    }
    int r = nb + wave * 16 + quad * 4 + reg;
    if (n15 == 0 && r < NN) {
      s1[r] = v1;
      s2[r] = v2;
    }
  }
}

// ---------------------------------------------------------------------------
// Edge scores
// ---------------------------------------------------------------------------
__global__ __launch_bounds__(256) void edge_k(const void* __restrict__ ei,
                                              const int* __restrict__ flag,
                                              const float* __restrict__ s1,
                                              const float* __restrict__ s2,
                                              const float* __restrict__ be,
                                              float* __restrict__ out) {
  int e = blockIdx.x * 256 + threadIdx.x;
  int is64 = *flag;
  int s = ld_idx(ei, is64, e);
  int d = ld_idx(ei, is64, (long long)NE + e);
  float v = s1[s] + s2[d] + be[0];
  out[e] = 1.0f / (1.0f + __expf(-v));
}

extern "C" void kernel_launch(void* const* d_in, const int* in_sizes, int n_in,
                              void* d_out, int out_size, void* d_ws, size_t ws_size,
                              hipStream_t stream) {
  const float* x   = (const float*)d_in[0];
  const void*  ei  = d_in[1];
  const float* Wl1 = (const float*)d_in[2];
  const float* bl1 = (const float*)d_in[3];
  const float* Wr1 = (const float*)d_in[4];
  const float* Wl2 = (const float*)d_in[5];
  const float* bl2 = (const float*)d_in[6];
  const float* Wr2 = (const float*)d_in[7];
  const float* We  = (const float*)d_in[8];
  const float* be  = (const float*)d_in[9];
  float* out = (float*)d_out;

  // Workspace (4B units): deg | offsets | srclist | xb | meanb | h1b | s1 |
  // s2 | flag | bsum | Wt1 | Wt2   (~42 MB)
  int* deg     = (int*)d_ws;
  int* offsets = deg + NN;
  int* srclist = offsets + 50004;
  ush_t* xb    = (ush_t*)(srclist + NE);
  ush_t* meanb = xb + (size_t)NN * DD;
  ush_t* h1b   = meanb + (size_t)NN * DD;
  float* s1    = (float*)(h1b + (size_t)NN * DD);
  float* s2    = s1 + NN;
  int* flag    = (int*)(s2 + NN);
  int* bsum    = flag + 4;
  ush_t* Wt1   = (ush_t*)(bsum + 256);
  ush_t* Wt2   = Wt1 + 32768;
  int* cursor  = (int*)s1;  // dead before sage_l2 writes s1

  detect_k<<<1, 64, 0, stream>>>(ei, flag);
  hipMemsetAsync(deg, 0, NN * sizeof(int), stream);
  pack_k<<<NN * DD / 4 / 256, 256, 0, stream>>>(x, xb);
  wprep_k<<<65536 / 256, 256, 0, stream>>>(Wl1, Wr1, Wl2, Wr2, Wt1, Wt2);

  count_k<<<NE / 256, 256, 0, stream>>>(ei, flag, deg);
  scan1_k<<<SB, 256, 0, stream>>>(deg, offsets, bsum);
  scan2_k<<<1, 256, 0, stream>>>(bsum);
  scan3_k<<<SB, 256, 0, stream>>>(bsum, offsets, cursor);
  fill_k<<<NE / 256, 256, 0, stream>>>(ei, flag, cursor, srclist);

  int gemm_blocks = (NN + 63) / 64;  // 782
  agg_k<<<(NN * 32) / 256, 256, 0, stream>>>(xb, srclist, offsets, meanb);
  sage_l1<<<gemm_blocks, 256, 0, stream>>>(meanb, xb, Wt1, bl1, h1b);

  agg_k<<<(NN * 32) / 256, 256, 0, stream>>>(h1b, srclist, offsets, meanb);
  sage_l2<<<gemm_blocks, 256, 0, stream>>>(meanb, h1b, Wt2, bl2, We, s1, s2);

  edge_k<<<NE / 256, 256, 0, stream>>>(ei, flag, s1, s2, be, out);
}

// Round 7
// 247.177 us; speedup vs baseline: 12.9301x; 1.2490x over previous
//
#include <hip/hip_runtime.h>

#define NN 50000
#define NE 800000
#define DD 128
#define BUCKETS 196   // ceil(NN/256) buckets of 256 nodes
#define PB 4096       // edges per part_k block
#define PBLK 196      // ceil(NE/PB)
#define EMAX 6144     // per-bucket edge cap (mean 4096, std 64 -> +32 sigma)
#define BPAD 264      // ushorts per col in LDS B (256 + 8 pad)

typedef unsigned int uint_t;
typedef unsigned short ush_t;
typedef __attribute__((ext_vector_type(8))) short short8;   // 8 bf16
typedef __attribute__((ext_vector_type(4))) float f32x4;    // MFMA C/D

// bf16 helpers
__device__ __forceinline__ float bflo(uint_t u) { return __uint_as_float(u << 16); }
__device__ __forceinline__ float bfhi(uint_t u) { return __uint_as_float(u & 0xffff0000u); }
__device__ __forceinline__ ush_t f2bf(float f) {  // RNE
  uint_t u = __float_as_uint(f);
  u += 0x7fffu + ((u >> 16) & 1u);
  return (ush_t)(u >> 16);
}
__device__ __forceinline__ uint2 pack4(float a, float b, float c, float d) {
  uint2 o;
  o.x = (uint_t)f2bf(a) | ((uint_t)f2bf(b) << 16);
  o.y = (uint_t)f2bf(c) | ((uint_t)f2bf(d) << 16);
  return o;
}

__device__ __forceinline__ int ld_idx(const void* ei, int is64, long long i) {
  return is64 ? (int)((const long long*)ei)[i] : ((const int*)ei)[i];
}

// Block-wide inclusive scan over 256 ints (wave shuffles + 4-wave combine).
__device__ __forceinline__ int block_incl_scan(int v, int tid, int* wsum) {
  int lane = tid & 63, wave = tid >> 6;
  int s = v;
#pragma unroll
  for (int off = 1; off < 64; off <<= 1) {
    int u = __shfl_up(s, off, 64);
    if (lane >= off) s += u;
  }
  if (lane == 63) wsum[wave] = s;
  __syncthreads();
  int base = 0;
  if (wave > 0) base += wsum[0];
  if (wave > 1) base += wsum[1];
  if (wave > 2) base += wsum[2];
  return base + s;
}

// ---------------------------------------------------------------------------
// prep_k: blocks 0..255 transpose+pack weights (Wt[layer][col][k] bf16, K=256
// combined [Wl;Wr]); block 256 detects index width + zeros bucket counters.
// ---------------------------------------------------------------------------
__global__ __launch_bounds__(256) void prep_k(
    const float* __restrict__ Wl1, const float* __restrict__ Wr1,
    const float* __restrict__ Wl2, const float* __restrict__ Wr2,
    ush_t* __restrict__ Wt1, ush_t* __restrict__ Wt2,
    const void* __restrict__ ei, int* __restrict__ flag,
    int* __restrict__ bcnt) {
  int tid = threadIdx.x;
  if (blockIdx.x == 256) {
    bcnt[tid] = 0;
    if (tid == 0) {
      const unsigned long long* p = (const unsigned long long*)ei;
      int is64 = 1;
      for (int i = 0; i < 64; ++i)
        if (p[i] >= (1ull << 32)) { is64 = 0; break; }
      *flag = is64;
    }
    return;
  }
  int e = blockIdx.x * 256 + tid;  // < 65536
  int layer = e >> 15;
  int r = e & 32767;
  int col = r >> 8;
  int k = r & 255;
  const float* Wl = layer ? Wl2 : Wl1;
  const float* Wr = layer ? Wr2 : Wr1;
  float v = (k < DD) ? Wl[k * DD + col] : Wr[(k - DD) * DD + col];
  ush_t* Wt = layer ? Wt2 : Wt1;
  Wt[col * 256 + k] = f2bf(v);
}

// ---------------------------------------------------------------------------
// Pack x fp32 -> bf16 (4 elems/thread).
// ---------------------------------------------------------------------------
__global__ __launch_bounds__(256) void pack_k(const float* __restrict__ src,
                                              ush_t* __restrict__ dst) {
  int i = blockIdx.x * 256 + threadIdx.x;
  float4 v = reinterpret_cast<const float4*>(src)[i];
  reinterpret_cast<uint2*>(dst)[i] = pack4(v.x, v.y, v.z, v.w);
}

// ---------------------------------------------------------------------------
// Bucket histogram: LDS-staged, one global atomic per (block,bucket).
// ---------------------------------------------------------------------------
__global__ __launch_bounds__(256) void bhist_k(const void* __restrict__ ei,
                                               const int* __restrict__ flag,
                                               int* __restrict__ bcnt) {
  __shared__ int h[256];
  int tid = threadIdx.x;
  h[tid] = 0;
  __syncthreads();
  int is64 = *flag;
  long long base = (long long)blockIdx.x * PB;
#pragma unroll
  for (int i = 0; i < PB / 256; ++i) {
    long long e = base + i * 256 + tid;
    if (e < NE) {
      int d = ld_idx(ei, is64, (long long)NE + e);
      atomicAdd(&h[d >> 8], 1);
    }
  }
  __syncthreads();
  if (h[tid]) atomicAdd(&bcnt[tid], h[tid]);
}

// ---------------------------------------------------------------------------
// Scan bucket counts -> bucket bases; seed partition cursors.
// ---------------------------------------------------------------------------
__global__ __launch_bounds__(256) void bscan_k(const int* __restrict__ bcnt,
                                               int* __restrict__ bbase,
                                               int* __restrict__ bcur) {
  __shared__ int wsum[4];
  int tid = threadIdx.x;
  int v = (tid < BUCKETS) ? bcnt[tid] : 0;
  int incl = block_incl_scan(v, tid, wsum);
  if (tid < BUCKETS) { bbase[tid] = incl - v; bcur[tid] = incl - v; }
  if (tid == 0) bbase[BUCKETS] = NE;
}

// ---------------------------------------------------------------------------
// Partition edges into buckets. Each block bins 4096 edges in LDS (packed
// (bucket<<24)|(tgt&255)<<16|src -- src < 2^16), reserves global ranges, then
// copies out bucket-ordered => coalesced runs (~84 B avg). No 4B scatter.
// ---------------------------------------------------------------------------
__global__ __launch_bounds__(256) void part_k(const void* __restrict__ ei,
                                              const int* __restrict__ flag,
                                              int* __restrict__ bcur,
                                              uint_t* __restrict__ pbuf) {
  __shared__ int hist[256];
  __shared__ int basel[256];
  __shared__ int cur[256];
  __shared__ int gbase[256];
  __shared__ int wsum[4];
  __shared__ uint_t buf[PB];
  __shared__ unsigned char bbuf[PB];
  int tid = threadIdx.x;
  hist[tid] = 0;
  __syncthreads();
  int is64 = *flag;
  long long base = (long long)blockIdx.x * PB;
  uint_t pv[PB / 256];
#pragma unroll
  for (int i = 0; i < PB / 256; ++i) {
    long long e = base + i * 256 + tid;
    if (e < NE) {
      int s = ld_idx(ei, is64, e);
      int d = ld_idx(ei, is64, (long long)NE + e);
      pv[i] = ((uint_t)(d >> 8) << 24) | ((uint_t)(d & 255) << 16) | (uint_t)s;
      atomicAdd(&hist[d >> 8], 1);
    } else {
      pv[i] = 0xFFFFFFFFu;  // invalid (real bucket <= 195)
    }
  }
  __syncthreads();
  int hv = hist[tid];
  int incl = block_incl_scan(hv, tid, wsum);
  basel[tid] = incl - hv;
  cur[tid] = incl - hv;
  if (hv > 0) gbase[tid] = atomicAdd(&bcur[tid], hv);
  __syncthreads();
#pragma unroll
  for (int i = 0; i < PB / 256; ++i) {
    uint_t p = pv[i];
    if (p != 0xFFFFFFFFu) {
      int b = p >> 24;
      int r = atomicAdd(&cur[b], 1);
      buf[r] = p & 0xFFFFFFu;  // (tgt_local<<16)|src
      bbuf[r] = (unsigned char)b;
    }
  }
  __syncthreads();
  int total = basel[255] + hist[255];
  for (int j = tid; j < total; j += 256) {
    int b = bbuf[j];
    pbuf[gbase[b] + (j - basel[b])] = buf[j];
  }
}

// ---------------------------------------------------------------------------
// Per-bucket CSR build: one block per bucket. LDS histogram -> node offsets
// (coalesced write), then scatter src into the bucket's contiguous srclist
// region. All scatter from ONE CU => lines assemble in one L2, no cross-XCD
// write amplification.
// ---------------------------------------------------------------------------
__global__ __launch_bounds__(256) void csr_k(const uint_t* __restrict__ pbuf,
                                             const int* __restrict__ bbase,
                                             int* __restrict__ offsets,
                                             int* __restrict__ srclist) {
  __shared__ int cnt[256];
  __shared__ int scur[256];
  __shared__ int wsum[4];
  __shared__ uint_t ebuf[EMAX];
  int tid = threadIdx.x;
  int b = blockIdx.x;
  cnt[tid] = 0;
  __syncthreads();
  int ebase = bbase[b];
  int ecnt = bbase[b + 1] - ebase;
  if (ecnt > EMAX) ecnt = EMAX;
  for (int j = tid; j < ecnt; j += 256) {
    uint_t v = pbuf[ebase + j];
    ebuf[j] = v;
    atomicAdd(&cnt[(v >> 16) & 255], 1);
  }
  __syncthreads();
  int c = cnt[tid];
  int incl = block_incl_scan(c, tid, wsum);
  int ex = incl - c;
  scur[tid] = ex;
  int node = b * 256 + tid;
  if (node < NN) offsets[node] = ebase + ex;
  if (b == BUCKETS - 1 && tid == 0) offsets[NN] = NE;
  __syncthreads();
  for (int j = tid; j < ecnt; j += 256) {
    uint_t v = ebuf[j];
    int p = atomicAdd(&scur[(v >> 16) & 255], 1);
    srclist[ebase + p] = (int)(v & 0xFFFFu);
  }
}

// ---------------------------------------------------------------------------
// Gather-mean over bf16 features.
// ---------------------------------------------------------------------------
__global__ __launch_bounds__(256) void agg_k(const ush_t* __restrict__ featb,
                                             const int* __restrict__ srclist,
                                             const int* __restrict__ offsets,
                                             ush_t* __restrict__ meanb) {
  int t = blockIdx.x * 256 + threadIdx.x;
  int node = t >> 5;
  int lane = t & 31;
  int f = lane << 2;
  int beg = offsets[node];
  int end = offsets[node + 1];
  float4 acc = make_float4(0.f, 0.f, 0.f, 0.f);
  for (int c = beg; c < end; c += 32) {
    int idx = c + lane;
    int sl = (idx < end) ? srclist[idx] : 0;
    int m = min(32, end - c);
    for (int jj = 0; jj < m; ++jj) {
      int s = __shfl(sl, jj, 32);
      uint2 v = *reinterpret_cast<const uint2*>(featb + (size_t)s * DD + f);
      acc.x += bflo(v.x); acc.y += bfhi(v.x);
      acc.z += bflo(v.y); acc.w += bfhi(v.y);
    }
  }
  float inv = 1.0f / fmaxf((float)(end - beg), 1.0f);
  *reinterpret_cast<uint2*>(meanb + (size_t)node * DD + f) =
      pack4(acc.x * inv, acc.y * inv, acc.z * inv, acc.w * inv);
}

// ---------------------------------------------------------------------------
// MFMA GEMM core: 4 waves/block, 64 node-rows/block, K=256 ([A0||A1] @ Wt).
// A-frags straight from global bf16; B staged in LDS (+8 ushort pad).
// ---------------------------------------------------------------------------
#define MFMA_CORE(A0PTR, A1PTR, WTPTR)                                         \
  int tid = threadIdx.x;                                                       \
  int lane = tid & 63;                                                         \
  int wave = tid >> 6;                                                         \
  int n15 = lane & 15, quad = lane >> 4;                                       \
  int nb = blockIdx.x * 64;                                                    \
  for (int it = 0; it < 16; ++it) {                                            \
    int i = it * 256 + tid;                                                    \
    int col = i >> 5, c = i & 31;                                              \
    *reinterpret_cast<short8*>(&sB[col * BPAD + c * 8]) =                      \
        reinterpret_cast<const short8*>(WTPTR)[i];                             \
  }                                                                            \
  __syncthreads();                                                             \
  int row = nb + wave * 16 + n15;                                              \
  int arow = (row < NN) ? row : (NN - 1);                                      \
  const ush_t* a0 = A0PTR + (size_t)arow * DD;                                 \
  const ush_t* a1 = A1PTR + (size_t)arow * DD;                                 \
  f32x4 acc[8];                                                                \
  _Pragma("unroll")                                                            \
  for (int t = 0; t < 8; ++t) acc[t] = (f32x4){0.f, 0.f, 0.f, 0.f};           \
  _Pragma("unroll")                                                            \
  for (int c = 0; c < 8; ++c) {                                                \
    const ush_t* ap = (c < 4) ? (a0 + c * 32 + quad * 8)                       \
                              : (a1 + (c - 4) * 32 + quad * 8);                \
    short8 af = *reinterpret_cast<const short8*>(ap);                          \
    int kb = c * 32 + quad * 8;                                                \
    _Pragma("unroll")                                                          \
    for (int t = 0; t < 8; ++t) {                                              \
      short8 bf = *reinterpret_cast<const short8*>(&sB[(t * 16 + n15) * BPAD + kb]); \
      acc[t] = __builtin_amdgcn_mfma_f32_16x16x32_bf16(af, bf, acc[t], 0, 0, 0); \
    }                                                                          \
  }

// ---------------------------------------------------------------------------
// Layer 1: h1 = relu([mean||x] @ Wt1 + bl1), bf16 out.
// ---------------------------------------------------------------------------
__global__ __launch_bounds__(256, 2) void sage_l1(
    const ush_t* __restrict__ meanb, const ush_t* __restrict__ xb,
    const ush_t* __restrict__ Wt1, const float* __restrict__ bl,
    ush_t* __restrict__ h1b) {
  __shared__ ush_t sB[128 * BPAD];
  MFMA_CORE(meanb, xb, Wt1)
#pragma unroll
  for (int t = 0; t < 8; ++t) {
    int col = t * 16 + n15;
    float b = bl[col];
#pragma unroll
    for (int reg = 0; reg < 4; ++reg) {
      int r = nb + wave * 16 + quad * 4 + reg;
      if (r < NN)
        h1b[(size_t)r * DD + col] = f2bf(fmaxf(acc[t][reg] + b, 0.f));
    }
  }
}

// ---------------------------------------------------------------------------
// Layer 2 + fused edge projection (h2 never stored).
// ---------------------------------------------------------------------------
__global__ __launch_bounds__(256, 2) void sage_l2(
    const ush_t* __restrict__ meanb, const ush_t* __restrict__ h1b,
    const ush_t* __restrict__ Wt2, const float* __restrict__ bl,
    const float* __restrict__ We, float* __restrict__ s1,
    float* __restrict__ s2) {
  __shared__ ush_t sB[128 * BPAD];
  MFMA_CORE(meanb, h1b, Wt2)
  float p1[4] = {0.f, 0.f, 0.f, 0.f};
  float p2[4] = {0.f, 0.f, 0.f, 0.f};
#pragma unroll
  for (int t = 0; t < 8; ++t) {
    int col = t * 16 + n15;
    float b = bl[col];
    float w1 = We[col];
    float w2 = We[DD + col];
#pragma unroll
    for (int reg = 0; reg < 4; ++reg) {
      float v = acc[t][reg] + b;
      p1[reg] += v * w1;
      p2[reg] += v * w2;
    }
  }
#pragma unroll
  for (int reg = 0; reg < 4; ++reg) {
    float v1 = p1[reg], v2 = p2[reg];
    for (int off = 8; off > 0; off >>= 1) {
      v1 += __shfl_down(v1, off, 16);
      v2 += __shfl_down(v2, off, 16);
    }
    int r = nb + wave * 16 + quad * 4 + reg;
    if (n15 == 0 && r < NN) {
      s1[r] = v1;
      s2[r] = v2;
    }
  }
}

// ---------------------------------------------------------------------------
// Edge scores
// ---------------------------------------------------------------------------
__global__ __launch_bounds__(256) void edge_k(const void* __restrict__ ei,
                                              const int* __restrict__ flag,
                                              const float* __restrict__ s1,
                                              const float* __restrict__ s2,
                                              const float* __restrict__ be,
                                              float* __restrict__ out) {
  int e = blockIdx.x * 256 + threadIdx.x;
  int is64 = *flag;
  int s = ld_idx(ei, is64, e);
  int d = ld_idx(ei, is64, (long long)NE + e);
  float v = s1[s] + s2[d] + be[0];
  out[e] = 1.0f / (1.0f + __expf(-v));
}

extern "C" void kernel_launch(void* const* d_in, const int* in_sizes, int n_in,
                              void* d_out, int out_size, void* d_ws, size_t ws_size,
                              hipStream_t stream) {
  const float* x   = (const float*)d_in[0];
  const void*  ei  = d_in[1];
  const float* Wl1 = (const float*)d_in[2];
  const float* bl1 = (const float*)d_in[3];
  const float* Wr1 = (const float*)d_in[4];
  const float* Wl2 = (const float*)d_in[5];
  const float* bl2 = (const float*)d_in[6];
  const float* Wr2 = (const float*)d_in[7];
  const float* We  = (const float*)d_in[8];
  const float* be  = (const float*)d_in[9];
  float* out = (float*)d_out;

  // Workspace (4B units): bcnt[256] | bbase[260] | bcur[256] | flag[4] |
  // offsets[NN+4] | pbuf[NE] | srclist[NE] | xb | meanb | h1b | s1 | s2 |
  // Wt1 | Wt2   (~45 MB)
  int* bcnt    = (int*)d_ws;
  int* bbase   = bcnt + 256;
  int* bcur    = bbase + 260;
  int* flag    = bcur + 256;
  int* offsets = flag + 4;
  uint_t* pbuf = (uint_t*)(offsets + NN + 4);
  int* srclist = (int*)(pbuf + NE);
  ush_t* xb    = (ush_t*)(srclist + NE);
  ush_t* meanb = xb + (size_t)NN * DD;
  ush_t* h1b   = meanb + (size_t)NN * DD;
  float* s1    = (float*)(h1b + (size_t)NN * DD);
  float* s2    = s1 + NN;
  ush_t* Wt1   = (ush_t*)(s2 + NN);
  ush_t* Wt2   = Wt1 + 32768;

  prep_k<<<257, 256, 0, stream>>>(Wl1, Wr1, Wl2, Wr2, Wt1, Wt2, ei, flag, bcnt);
  pack_k<<<NN * DD / 4 / 256, 256, 0, stream>>>(x, xb);

  // CSR build: histogram -> scan -> LDS-binned partition -> per-bucket CSR
  bhist_k<<<PBLK, 256, 0, stream>>>(ei, flag, bcnt);
  bscan_k<<<1, 256, 0, stream>>>(bcnt, bbase, bcur);
  part_k<<<PBLK, 256, 0, stream>>>(ei, flag, bcur, pbuf);
  csr_k<<<BUCKETS, 256, 0, stream>>>(pbuf, bbase, offsets, srclist);

  int gemm_blocks = (NN + 63) / 64;  // 782
  agg_k<<<(NN * 32) / 256, 256, 0, stream>>>(xb, srclist, offsets, meanb);
  sage_l1<<<gemm_blocks, 256, 0, stream>>>(meanb, xb, Wt1, bl1, h1b);

  agg_k<<<(NN * 32) / 256, 256, 0, stream>>>(h1b, srclist, offsets, meanb);
  sage_l2<<<gemm_blocks, 256, 0, stream>>>(meanb, h1b, Wt2, bl2, We, s1, s2);

  edge_k<<<NE / 256, 256, 0, stream>>>(ei, flag, s1, s2, be, out);
}

// Round 8
// 221.842 us; speedup vs baseline: 14.4068x; 1.1142x over previous
//
#include <hip/hip_runtime.h>

#define NN 50000
#define NE 800000
#define DD 128
#define BUCKETS 196   // ceil(NN/256) buckets of 256 nodes
#define PB 4096       // edges per part_k block
#define PBLK 196      // ceil(NE/PB)
#define EMAX 6144     // per-bucket edge cap (mean 4096, sigma 64 -> +32 sigma)
#define BPAD 264      // ushorts per col in LDS B (256 + 8 pad)
#define PACKB 6250    // pack blocks: NN*DD/4/256

typedef unsigned int uint_t;
typedef unsigned short ush_t;
typedef __attribute__((ext_vector_type(8))) short short8;   // 8 bf16
typedef __attribute__((ext_vector_type(4))) float f32x4;    // MFMA C/D

// bf16 helpers
__device__ __forceinline__ float bflo(uint_t u) { return __uint_as_float(u << 16); }
__device__ __forceinline__ float bfhi(uint_t u) { return __uint_as_float(u & 0xffff0000u); }
__device__ __forceinline__ ush_t f2bf(float f) {  // RNE
  uint_t u = __float_as_uint(f);
  u += 0x7fffu + ((u >> 16) & 1u);
  return (ush_t)(u >> 16);
}
__device__ __forceinline__ uint2 pack4(float a, float b, float c, float d) {
  uint2 o;
  o.x = (uint_t)f2bf(a) | ((uint_t)f2bf(b) << 16);
  o.y = (uint_t)f2bf(c) | ((uint_t)f2bf(d) << 16);
  return o;
}

__device__ __forceinline__ int ld_idx(const void* ei, int is64, long long i) {
  return is64 ? (int)((const long long*)ei)[i] : ((const int*)ei)[i];
}

// Block-wide inclusive scan over 256 ints (wave shuffles + 4-wave combine).
__device__ __forceinline__ int block_incl_scan(int v, int tid, int* wsum) {
  int lane = tid & 63, wave = tid >> 6;
  int s = v;
#pragma unroll
  for (int off = 1; off < 64; off <<= 1) {
    int u = __shfl_up(s, off, 64);
    if (lane >= off) s += u;
  }
  if (lane == 63) wsum[wave] = s;
  __syncthreads();
  int base = 0;
  if (wave > 0) base += wsum[0];
  if (wave > 1) base += wsum[1];
  if (wave > 2) base += wsum[2];
  return base + s;
}

// ---------------------------------------------------------------------------
// prep_k (fused): blocks 0..PACKB-1 pack x fp32->bf16; next 256 blocks
// transpose+pack weights (Wt[layer][col][k], K=256 = [Wl;Wr]); last block
// detects index width and zeros the bucket cursors.
// ---------------------------------------------------------------------------
__global__ __launch_bounds__(256) void prep_k(
    const float* __restrict__ x, ush_t* __restrict__ xb,
    const float* __restrict__ Wl1, const float* __restrict__ Wr1,
    const float* __restrict__ Wl2, const float* __restrict__ Wr2,
    ush_t* __restrict__ Wt1, ush_t* __restrict__ Wt2,
    const void* __restrict__ ei, int* __restrict__ flag,
    int* __restrict__ bcur) {
  int tid = threadIdx.x;
  int blk = blockIdx.x;
  if (blk < PACKB) {
    int i = blk * 256 + tid;
    float4 v = reinterpret_cast<const float4*>(x)[i];
    reinterpret_cast<uint2*>(xb)[i] = pack4(v.x, v.y, v.z, v.w);
    return;
  }
  blk -= PACKB;
  if (blk < 256) {
    int e = blk * 256 + tid;  // < 65536
    int layer = e >> 15;
    int r = e & 32767;
    int col = r >> 8;
    int k = r & 255;
    const float* Wl = layer ? Wl2 : Wl1;
    const float* Wr = layer ? Wr2 : Wr1;
    float v = (k < DD) ? Wl[k * DD + col] : Wr[(k - DD) * DD + col];
    ush_t* Wt = layer ? Wt2 : Wt1;
    Wt[col * 256 + k] = f2bf(v);
    return;
  }
  // control block
  bcur[tid] = 0;
  if (tid == 0) {
    const unsigned long long* p = (const unsigned long long*)ei;
    int is64 = 1;
    for (int i = 0; i < 64; ++i)
      if (p[i] >= (1ull << 32)) { is64 = 0; break; }
    *flag = is64;
  }
}

// ---------------------------------------------------------------------------
// Partition edges into fixed-capacity bucket slots (pbuf[b*EMAX + ...]).
// Each block bins 4096 edges in LDS (packed (bucket<<24)|(tgt&255)<<16|src,
// src < 2^16), reserves per-bucket ranges with one atomic, copies out
// bucket-ordered => coalesced ~84 B runs. Edges read exactly once.
// ---------------------------------------------------------------------------
__global__ __launch_bounds__(256) void part_k(const void* __restrict__ ei,
                                              const int* __restrict__ flag,
                                              int* __restrict__ bcur,
                                              uint_t* __restrict__ pbuf) {
  __shared__ int hist[256];
  __shared__ int basel[256];
  __shared__ int cur[256];
  __shared__ int gbase[256];
  __shared__ int wsum[4];
  __shared__ uint_t buf[PB];
  __shared__ unsigned char bbuf[PB];
  int tid = threadIdx.x;
  hist[tid] = 0;
  __syncthreads();
  int is64 = *flag;
  long long base = (long long)blockIdx.x * PB;
  uint_t pv[PB / 256];
#pragma unroll
  for (int i = 0; i < PB / 256; ++i) {
    long long e = base + i * 256 + tid;
    if (e < NE) {
      int s = ld_idx(ei, is64, e);
      int d = ld_idx(ei, is64, (long long)NE + e);
      pv[i] = ((uint_t)(d >> 8) << 24) | ((uint_t)(d & 255) << 16) | (uint_t)s;
      atomicAdd(&hist[d >> 8], 1);
    } else {
      pv[i] = 0xFFFFFFFFu;  // invalid (real bucket <= 195)
    }
  }
  __syncthreads();
  int hv = hist[tid];
  int incl = block_incl_scan(hv, tid, wsum);
  basel[tid] = incl - hv;
  cur[tid] = incl - hv;
  if (hv > 0) gbase[tid] = atomicAdd(&bcur[tid], hv);
  __syncthreads();
#pragma unroll
  for (int i = 0; i < PB / 256; ++i) {
    uint_t p = pv[i];
    if (p != 0xFFFFFFFFu) {
      int b = p >> 24;
      int r = atomicAdd(&cur[b], 1);
      buf[r] = p & 0xFFFFFFu;  // (tgt_local<<16)|src
      bbuf[r] = (unsigned char)b;
    }
  }
  __syncthreads();
  int total = basel[255] + hist[255];
  for (int j = tid; j < total; j += 256) {
    int b = bbuf[j];
    int slot = gbase[b] + (j - basel[b]);
    if (slot < EMAX) pbuf[(size_t)b * EMAX + slot] = buf[j];
  }
}

// ---------------------------------------------------------------------------
// Per-bucket CSR build (one block per bucket). Each block redundantly scans
// the 196 bucket counts in LDS (cheap) for its global base, then LDS node
// histogram -> offsets (coalesced) + scatter src into its contiguous region.
// Single-CU scatter => no cross-XCD write amplification.
// ---------------------------------------------------------------------------
__global__ __launch_bounds__(256) void csr_k(const uint_t* __restrict__ pbuf,
                                             const int* __restrict__ bcur,
                                             int* __restrict__ offsets,
                                             int* __restrict__ srclist) {
  __shared__ int cnt[256];
  __shared__ int scur[256];
  __shared__ int wsum[4];
  __shared__ int sgb, scnt, stot;
  __shared__ uint_t ebuf[EMAX];
  int tid = threadIdx.x;
  int b = blockIdx.x;
  // bucket-base scan (all blocks redundantly)
  int v = 0;
  if (tid < BUCKETS) {
    v = bcur[tid];
    if (v > EMAX) v = EMAX;
  }
  int incl = block_incl_scan(v, tid, wsum);
  if (tid == b) { sgb = incl - v; scnt = v; }
  if (tid == BUCKETS - 1) stot = incl;
  cnt[tid] = 0;
  __syncthreads();
  int gb = sgb;
  int ecnt = scnt;
  for (int j = tid; j < ecnt; j += 256) {
    uint_t e = pbuf[(size_t)b * EMAX + j];
    ebuf[j] = e;
    atomicAdd(&cnt[(e >> 16) & 255], 1);
  }
  __syncthreads();
  int c = cnt[tid];
  int incl2 = block_incl_scan(c, tid, wsum);
  int ex = incl2 - c;
  scur[tid] = ex;
  int node = b * 256 + tid;
  if (node < NN) offsets[node] = gb + ex;
  if (b == BUCKETS - 1 && tid == 0) offsets[NN] = stot;
  __syncthreads();
  for (int j = tid; j < ecnt; j += 256) {
    uint_t e = ebuf[j];
    int p = atomicAdd(&scur[(e >> 16) & 255], 1);
    srclist[gb + p] = (int)(e & 0xFFFFu);
  }
}

// ---------------------------------------------------------------------------
// Gather-mean over bf16 features. 32 lanes/node; edge list chunked 32-wide
// (coalesced) then broadcast; INNER UNROLL x4 keeps 4 independent row-gathers
// in flight per lane (latency-bound fix).
// ---------------------------------------------------------------------------
__global__ __launch_bounds__(256) void agg_k(const ush_t* __restrict__ featb,
                                             const int* __restrict__ srclist,
                                             const int* __restrict__ offsets,
                                             ush_t* __restrict__ meanb) {
  int t = blockIdx.x * 256 + threadIdx.x;
  int node = t >> 5;
  int lane = t & 31;
  int f = lane << 2;
  int beg = offsets[node];
  int end = offsets[node + 1];
  float4 acc = make_float4(0.f, 0.f, 0.f, 0.f);
  for (int c = beg; c < end; c += 32) {
    int idx = c + lane;
    int sl = (idx < end) ? srclist[idx] : 0;
    int m = min(32, end - c);
    int jj = 0;
    for (; jj + 4 <= m; jj += 4) {
      int s0 = __shfl(sl, jj, 32);
      int s1 = __shfl(sl, jj + 1, 32);
      int s2 = __shfl(sl, jj + 2, 32);
      int s3 = __shfl(sl, jj + 3, 32);
      uint2 v0 = *reinterpret_cast<const uint2*>(featb + (size_t)s0 * DD + f);
      uint2 v1 = *reinterpret_cast<const uint2*>(featb + (size_t)s1 * DD + f);
      uint2 v2 = *reinterpret_cast<const uint2*>(featb + (size_t)s2 * DD + f);
      uint2 v3 = *reinterpret_cast<const uint2*>(featb + (size_t)s3 * DD + f);
      acc.x += bflo(v0.x); acc.y += bfhi(v0.x); acc.z += bflo(v0.y); acc.w += bfhi(v0.y);
      acc.x += bflo(v1.x); acc.y += bfhi(v1.x); acc.z += bflo(v1.y); acc.w += bfhi(v1.y);
      acc.x += bflo(v2.x); acc.y += bfhi(v2.x); acc.z += bflo(v2.y); acc.w += bfhi(v2.y);
      acc.x += bflo(v3.x); acc.y += bfhi(v3.x); acc.z += bflo(v3.y); acc.w += bfhi(v3.y);
    }
    for (; jj < m; ++jj) {
      int s = __shfl(sl, jj, 32);
      uint2 v = *reinterpret_cast<const uint2*>(featb + (size_t)s * DD + f);
      acc.x += bflo(v.x); acc.y += bfhi(v.x);
      acc.z += bflo(v.y); acc.w += bfhi(v.y);
    }
  }
  float inv = 1.0f / fmaxf((float)(end - beg), 1.0f);
  *reinterpret_cast<uint2*>(meanb + (size_t)node * DD + f) =
      pack4(acc.x * inv, acc.y * inv, acc.z * inv, acc.w * inv);
}

// ---------------------------------------------------------------------------
// MFMA GEMM core: 4 waves/block, 64 node-rows/block, K=256 ([A0||A1] @ Wt).
// A-frags straight from global bf16; B staged in LDS (+8 ushort pad).
// ---------------------------------------------------------------------------
#define MFMA_CORE(A0PTR, A1PTR, WTPTR)                                         \
  int tid = threadIdx.x;                                                       \
  int lane = tid & 63;                                                         \
  int wave = tid >> 6;                                                         \
  int n15 = lane & 15, quad = lane >> 4;                                       \
  int nb = blockIdx.x * 64;                                                    \
  for (int it = 0; it < 16; ++it) {                                            \
    int i = it * 256 + tid;                                                    \
    int col = i >> 5, c = i & 31;                                              \
    *reinterpret_cast<short8*>(&sB[col * BPAD + c * 8]) =                      \
        reinterpret_cast<const short8*>(WTPTR)[i];                             \
  }                                                                            \
  __syncthreads();                                                             \
  int row = nb + wave * 16 + n15;                                              \
  int arow = (row < NN) ? row : (NN - 1);                                      \
  const ush_t* a0 = A0PTR + (size_t)arow * DD;                                 \
  const ush_t* a1 = A1PTR + (size_t)arow * DD;                                 \
  f32x4 acc[8];                                                                \
  _Pragma("unroll")                                                            \
  for (int t = 0; t < 8; ++t) acc[t] = (f32x4){0.f, 0.f, 0.f, 0.f};           \
  _Pragma("unroll")                                                            \
  for (int c = 0; c < 8; ++c) {                                                \
    const ush_t* ap = (c < 4) ? (a0 + c * 32 + quad * 8)                       \
                              : (a1 + (c - 4) * 32 + quad * 8);                \
    short8 af = *reinterpret_cast<const short8*>(ap);                          \
    int kb = c * 32 + quad * 8;                                                \
    _Pragma("unroll")                                                          \
    for (int t = 0; t < 8; ++t) {                                              \
      short8 bf = *reinterpret_cast<const short8*>(&sB[(t * 16 + n15) * BPAD + kb]); \
      acc[t] = __builtin_amdgcn_mfma_f32_16x16x32_bf16(af, bf, acc[t], 0, 0, 0); \
    }                                                                          \
  }

// ---------------------------------------------------------------------------
// Layer 1: h1 = relu([mean||x] @ Wt1 + bl1), bf16 out.
// ---------------------------------------------------------------------------
__global__ __launch_bounds__(256, 2) void sage_l1(
    const ush_t* __restrict__ meanb, const ush_t* __restrict__ xb,
    const ush_t* __restrict__ Wt1, const float* __restrict__ bl,
    ush_t* __restrict__ h1b) {
  __shared__ ush_t sB[128 * BPAD];
  MFMA_CORE(meanb, xb, Wt1)
#pragma unroll
  for (int t = 0; t < 8; ++t) {
    int col = t * 16 + n15;
    float b = bl[col];
#pragma unroll
    for (int reg = 0; reg < 4; ++reg) {
      int r = nb + wave * 16 + quad * 4 + reg;
      if (r < NN)
        h1b[(size_t)r * DD + col] = f2bf(fmaxf(acc[t][reg] + b, 0.f));
    }
  }
}

// ---------------------------------------------------------------------------
// Layer 2 + fused edge projection (h2 never stored).
// ---------------------------------------------------------------------------
__global__ __launch_bounds__(256, 2) void sage_l2(
    const ush_t* __restrict__ meanb, const ush_t* __restrict__ h1b,
    const ush_t* __restrict__ Wt2, const float* __restrict__ bl,
    const float* __restrict__ We, float* __restrict__ s1,
    float* __restrict__ s2) {
  __shared__ ush_t sB[128 * BPAD];
  MFMA_CORE(meanb, h1b, Wt2)
  float p1[4] = {0.f, 0.f, 0.f, 0.f};
  float p2[4] = {0.f, 0.f, 0.f, 0.f};
#pragma unroll
  for (int t = 0; t < 8; ++t) {
    int col = t * 16 + n15;
    float b = bl[col];
    float w1 = We[col];
    float w2 = We[DD + col];
#pragma unroll
    for (int reg = 0; reg < 4; ++reg) {
      float v = acc[t][reg] + b;
      p1[reg] += v * w1;
      p2[reg] += v * w2;
    }
  }
#pragma unroll
  for (int reg = 0; reg < 4; ++reg) {
    float v1 = p1[reg], v2 = p2[reg];
    for (int off = 8; off > 0; off >>= 1) {
      v1 += __shfl_down(v1, off, 16);
      v2 += __shfl_down(v2, off, 16);
    }
    int r = nb + wave * 16 + quad * 4 + reg;
    if (n15 == 0 && r < NN) {
      s1[r] = v1;
      s2[r] = v2;
    }
  }
}

// ---------------------------------------------------------------------------
// Edge scores
// ---------------------------------------------------------------------------
__global__ __launch_bounds__(256) void edge_k(const void* __restrict__ ei,
                                              const int* __restrict__ flag,
                                              const float* __restrict__ s1,
                                              const float* __restrict__ s2,
                                              const float* __restrict__ be,
                                              float* __restrict__ out) {
  int e = blockIdx.x * 256 + threadIdx.x;
  int is64 = *flag;
  int s = ld_idx(ei, is64, e);
  int d = ld_idx(ei, is64, (long long)NE + e);
  float v = s1[s] + s2[d] + be[0];
  out[e] = 1.0f / (1.0f + __expf(-v));
}

extern "C" void kernel_launch(void* const* d_in, const int* in_sizes, int n_in,
                              void* d_out, int out_size, void* d_ws, size_t ws_size,
                              hipStream_t stream) {
  const float* x   = (const float*)d_in[0];
  const void*  ei  = d_in[1];
  const float* Wl1 = (const float*)d_in[2];
  const float* bl1 = (const float*)d_in[3];
  const float* Wr1 = (const float*)d_in[4];
  const float* Wl2 = (const float*)d_in[5];
  const float* bl2 = (const float*)d_in[6];
  const float* Wr2 = (const float*)d_in[7];
  const float* We  = (const float*)d_in[8];
  const float* be  = (const float*)d_in[9];
  float* out = (float*)d_out;

  // Workspace (4B units): bcur[256] | flag[4] | offsets[NN+4] |
  // pbuf[BUCKETS*EMAX] | srclist[NE] | xb | meanb | h1b | s1 | s2 | Wt1 | Wt2
  int* bcur    = (int*)d_ws;
  int* flag    = bcur + 256;
  int* offsets = flag + 4;
  uint_t* pbuf = (uint_t*)(offsets + NN + 4);
  int* srclist = (int*)(pbuf + (size_t)BUCKETS * EMAX);
  ush_t* xb    = (ush_t*)(srclist + NE);
  ush_t* meanb = xb + (size_t)NN * DD;
  ush_t* h1b   = meanb + (size_t)NN * DD;
  float* s1    = (float*)(h1b + (size_t)NN * DD);
  float* s2    = s1 + NN;
  ush_t* Wt1   = (ush_t*)(s2 + NN);
  ush_t* Wt2   = Wt1 + 32768;

  prep_k<<<PACKB + 257, 256, 0, stream>>>(x, xb, Wl1, Wr1, Wl2, Wr2, Wt1, Wt2,
                                          ei, flag, bcur);
  part_k<<<PBLK, 256, 0, stream>>>(ei, flag, bcur, pbuf);
  csr_k<<<BUCKETS, 256, 0, stream>>>(pbuf, bcur, offsets, srclist);

  int gemm_blocks = (NN + 63) / 64;  // 782
  agg_k<<<(NN * 32) / 256, 256, 0, stream>>>(xb, srclist, offsets, meanb);
  sage_l1<<<gemm_blocks, 256, 0, stream>>>(meanb, xb, Wt1, bl1, h1b);

  agg_k<<<(NN * 32) / 256, 256, 0, stream>>>(h1b, srclist, offsets, meanb);
  sage_l2<<<gemm_blocks, 256, 0, stream>>>(meanb, h1b, Wt2, bl2, We, s1, s2);

  edge_k<<<NE / 256, 256, 0, stream>>>(ei, flag, s1, s2, be, out);
}

// Round 9
// 220.219 us; speedup vs baseline: 14.5129x; 1.0074x over previous
//
#include <hip/hip_runtime.h>

#define NN 50000
#define NE 800000
#define DD 128
#define BUCKETS 196   // ceil(NN/256) buckets of 256 nodes
#define PB 4096       // edges per partition block
#define PBLK 196      // ceil(NE/PB)
#define EMAX 6144     // per-bucket edge cap (mean 4096, sigma 64 -> +32 sigma)
#define BPAD 264      // ushorts per col in LDS B (256 + 8 pad)
#define PACKB 6250    // x-pack blocks: NN*DD/4/256

typedef unsigned int uint_t;
typedef unsigned short ush_t;
typedef __attribute__((ext_vector_type(8))) short short8;   // 8 bf16
typedef __attribute__((ext_vector_type(4))) float f32x4;    // MFMA C/D

// bf16 helpers
__device__ __forceinline__ float bflo(uint_t u) { return __uint_as_float(u << 16); }
__device__ __forceinline__ float bfhi(uint_t u) { return __uint_as_float(u & 0xffff0000u); }
__device__ __forceinline__ ush_t f2bf(float f) {  // RNE
  uint_t u = __float_as_uint(f);
  u += 0x7fffu + ((u >> 16) & 1u);
  return (ush_t)(u >> 16);
}
__device__ __forceinline__ uint_t pack2(float a, float b) {
  return (uint_t)f2bf(a) | ((uint_t)f2bf(b) << 16);
}

__device__ __forceinline__ int ld_idx(const void* ei, int is64, long long i) {
  return is64 ? (int)((const long long*)ei)[i] : ((const int*)ei)[i];
}

// Per-wave inline index-width detect: u64 view of int32 pairs has nonzero
// high words almost surely within the first 64 entries; true int64 indices
// (< 50000) never do. Uniform across waves, no sync needed.
__device__ __forceinline__ int detect64(const void* ei) {
  const unsigned long long* p = (const unsigned long long*)ei;
  unsigned long long w = p[threadIdx.x & 63];
  return __ballot((w >> 32) != 0) == 0ull ? 1 : 0;
}

// Block-wide inclusive scan over 256 ints (wave shuffles + 4-wave combine).
__device__ __forceinline__ int block_incl_scan(int v, int tid, int* wsum) {
  int lane = tid & 63, wave = tid >> 6;
  int s = v;
#pragma unroll
  for (int off = 1; off < 64; off <<= 1) {
    int u = __shfl_up(s, off, 64);
    if (lane >= off) s += u;
  }
  if (lane == 63) wsum[wave] = s;
  __syncthreads();
  int base = 0;
  if (wave > 0) base += wsum[0];
  if (wave > 1) base += wsum[1];
  if (wave > 2) base += wsum[2];
  return base + s;
}

// ---------------------------------------------------------------------------
// Fused prep+partition kernel.
//   blocks [0, PBLK):            partition edges into bucket slots + emit epk
//   blocks [PBLK, PBLK+PACKB):   pack x fp32->bf16
//   blocks [PBLK+PACKB, +256):   weight transpose+pack (Wt[col][k], K=256)
// Partition blocks are dispatched first so the latency-heavy phase leads.
// bcur must be zeroed before launch (hipMemsetAsync).
// ---------------------------------------------------------------------------
__global__ __launch_bounds__(256) void prep_part_k(
    const void* __restrict__ ei, int* __restrict__ bcur,
    uint_t* __restrict__ pbuf, uint_t* __restrict__ epk,
    const float* __restrict__ x, ush_t* __restrict__ xb,
    const float* __restrict__ Wl1, const float* __restrict__ Wr1,
    const float* __restrict__ Wl2, const float* __restrict__ Wr2,
    ush_t* __restrict__ Wt1, ush_t* __restrict__ Wt2) {
  __shared__ int hist[256];
  __shared__ int basel[256];
  __shared__ int cur[256];
  __shared__ int gbase[256];
  __shared__ int wsum[4];
  __shared__ uint_t buf[PB];
  __shared__ unsigned char bbuf[PB];
  int tid = threadIdx.x;
  int blk = blockIdx.x;
  if (blk >= PBLK) {
    blk -= PBLK;
    if (blk < PACKB) {  // pack x
      int i = blk * 256 + tid;
      float4 v = reinterpret_cast<const float4*>(x)[i];
      uint2 o;
      o.x = pack2(v.x, v.y);
      o.y = pack2(v.z, v.w);
      reinterpret_cast<uint2*>(xb)[i] = o;
      return;
    }
    blk -= PACKB;  // weight transpose: blk in [0,256)
    int e = blk * 256 + tid;  // < 65536
    int layer = e >> 15;
    int r = e & 32767;
    int col = r >> 8;
    int k = r & 255;
    const float* Wl = layer ? Wl2 : Wl1;
    const float* Wr = layer ? Wr2 : Wr1;
    float v = (k < DD) ? Wl[k * DD + col] : Wr[(k - DD) * DD + col];
    ush_t* Wt = layer ? Wt2 : Wt1;
    Wt[col * 256 + k] = f2bf(v);
    return;
  }
  // ---- partition region ----
  int is64 = detect64(ei);
  hist[tid] = 0;
  __syncthreads();
  long long base = (long long)blk * PB;
  uint_t pv[PB / 256];
#pragma unroll
  for (int i = 0; i < PB / 256; ++i) {
    long long e = base + i * 256 + tid;
    if (e < NE) {
      int s = ld_idx(ei, is64, e);
      int d = ld_idx(ei, is64, (long long)NE + e);
      pv[i] = ((uint_t)(d >> 8) << 24) | ((uint_t)(d & 255) << 16) | (uint_t)s;
      epk[e] = ((uint_t)d << 16) | (uint_t)s;  // original-order compact edges
      atomicAdd(&hist[d >> 8], 1);
    } else {
      pv[i] = 0xFFFFFFFFu;  // invalid (real bucket <= 195)
    }
  }
  __syncthreads();
  int hv = hist[tid];
  int incl = block_incl_scan(hv, tid, wsum);
  basel[tid] = incl - hv;
  cur[tid] = incl - hv;
  if (hv > 0) gbase[tid] = atomicAdd(&bcur[tid], hv);
  __syncthreads();
#pragma unroll
  for (int i = 0; i < PB / 256; ++i) {
    uint_t p = pv[i];
    if (p != 0xFFFFFFFFu) {
      int b = p >> 24;
      int r = atomicAdd(&cur[b], 1);
      buf[r] = p & 0xFFFFFFu;  // (tgt_local<<16)|src
      bbuf[r] = (unsigned char)b;
    }
  }
  __syncthreads();
  int total = basel[255] + hist[255];
  for (int j = tid; j < total; j += 256) {
    int b = bbuf[j];
    int slot = gbase[b] + (j - basel[b]);
    if (slot < EMAX) pbuf[(size_t)b * EMAX + slot] = buf[j];
  }
}

// ---------------------------------------------------------------------------
// Per-bucket CSR build (one block per bucket); single-CU scatter => no
// cross-XCD write amplification. Redundant per-block scan of bucket counts.
// ---------------------------------------------------------------------------
__global__ __launch_bounds__(256) void csr_k(const uint_t* __restrict__ pbuf,
                                             const int* __restrict__ bcur,
                                             int* __restrict__ offsets,
                                             int* __restrict__ srclist) {
  __shared__ int cnt[256];
  __shared__ int scur[256];
  __shared__ int wsum[4];
  __shared__ int sgb, scnt, stot;
  __shared__ uint_t ebuf[EMAX];
  int tid = threadIdx.x;
  int b = blockIdx.x;
  int v = 0;
  if (tid < BUCKETS) {
    v = bcur[tid];
    if (v > EMAX) v = EMAX;
  }
  int incl = block_incl_scan(v, tid, wsum);
  if (tid == b) { sgb = incl - v; scnt = v; }
  if (tid == BUCKETS - 1) stot = incl;
  cnt[tid] = 0;
  __syncthreads();
  int gb = sgb;
  int ecnt = scnt;
  for (int j = tid; j < ecnt; j += 256) {
    uint_t e = pbuf[(size_t)b * EMAX + j];
    ebuf[j] = e;
    atomicAdd(&cnt[(e >> 16) & 255], 1);
  }
  __syncthreads();
  int c = cnt[tid];
  int incl2 = block_incl_scan(c, tid, wsum);
  int ex = incl2 - c;
  scur[tid] = ex;
  int node = b * 256 + tid;
  if (node < NN) offsets[node] = gb + ex;
  if (b == BUCKETS - 1 && tid == 0) offsets[NN] = stot;
  __syncthreads();
  for (int j = tid; j < ecnt; j += 256) {
    uint_t e = ebuf[j];
    int p = atomicAdd(&scur[(e >> 16) & 255], 1);
    srclist[gb + p] = (int)(e & 0xFFFFu);
  }
}

// ---------------------------------------------------------------------------
// Gather-mean over bf16 features. 16 lanes/node, uint4 (8 bf16 = 16 B) per
// lane; srclist chunked 16-wide (coalesced) then shuffle-broadcast; unroll x4
// keeps 64 B of independent gathers in flight per lane.
// ---------------------------------------------------------------------------
__global__ __launch_bounds__(256) void agg_k(const ush_t* __restrict__ featb,
                                             const int* __restrict__ srclist,
                                             const int* __restrict__ offsets,
                                             ush_t* __restrict__ meanb) {
  int t = blockIdx.x * 256 + threadIdx.x;
  int node = t >> 4;
  int lane = t & 15;
  int f = lane << 3;  // 8 ushorts = 16 B
  int beg = offsets[node];
  int end = offsets[node + 1];
  float a0 = 0.f, a1 = 0.f, a2 = 0.f, a3 = 0.f, a4 = 0.f, a5 = 0.f, a6 = 0.f, a7 = 0.f;
  for (int c = beg; c < end; c += 16) {
    int idx = c + lane;
    int sl = (idx < end) ? srclist[idx] : 0;
    int m = min(16, end - c);
    int jj = 0;
    for (; jj + 4 <= m; jj += 4) {
      int s0 = __shfl(sl, jj, 16);
      int s1 = __shfl(sl, jj + 1, 16);
      int s2 = __shfl(sl, jj + 2, 16);
      int s3 = __shfl(sl, jj + 3, 16);
      uint4 v0 = *reinterpret_cast<const uint4*>(featb + (size_t)s0 * DD + f);
      uint4 v1 = *reinterpret_cast<const uint4*>(featb + (size_t)s1 * DD + f);
      uint4 v2 = *reinterpret_cast<const uint4*>(featb + (size_t)s2 * DD + f);
      uint4 v3 = *reinterpret_cast<const uint4*>(featb + (size_t)s3 * DD + f);
      a0 += bflo(v0.x); a1 += bfhi(v0.x); a2 += bflo(v0.y); a3 += bfhi(v0.y);
      a4 += bflo(v0.z); a5 += bfhi(v0.z); a6 += bflo(v0.w); a7 += bfhi(v0.w);
      a0 += bflo(v1.x); a1 += bfhi(v1.x); a2 += bflo(v1.y); a3 += bfhi(v1.y);
      a4 += bflo(v1.z); a5 += bfhi(v1.z); a6 += bflo(v1.w); a7 += bfhi(v1.w);
      a0 += bflo(v2.x); a1 += bfhi(v2.x); a2 += bflo(v2.y); a3 += bfhi(v2.y);
      a4 += bflo(v2.z); a5 += bfhi(v2.z); a6 += bflo(v2.w); a7 += bfhi(v2.w);
      a0 += bflo(v3.x); a1 += bfhi(v3.x); a2 += bflo(v3.y); a3 += bfhi(v3.y);
      a4 += bflo(v3.z); a5 += bfhi(v3.z); a6 += bflo(v3.w); a7 += bfhi(v3.w);
    }
    for (; jj < m; ++jj) {
      int s = __shfl(sl, jj, 16);
      uint4 v = *reinterpret_cast<const uint4*>(featb + (size_t)s * DD + f);
      a0 += bflo(v.x); a1 += bfhi(v.x); a2 += bflo(v.y); a3 += bfhi(v.y);
      a4 += bflo(v.z); a5 += bfhi(v.z); a6 += bflo(v.w); a7 += bfhi(v.w);
    }
  }
  float inv = 1.0f / fmaxf((float)(end - beg), 1.0f);
  uint4 o;
  o.x = pack2(a0 * inv, a1 * inv);
  o.y = pack2(a2 * inv, a3 * inv);
  o.z = pack2(a4 * inv, a5 * inv);
  o.w = pack2(a6 * inv, a7 * inv);
  *reinterpret_cast<uint4*>(meanb + (size_t)node * DD + f) = o;
}

// ---------------------------------------------------------------------------
// MFMA GEMM core: 4 waves/block, 64 node-rows/block, K=256 ([A0||A1] @ Wt).
// A-frags straight from global bf16; B staged in LDS (+8 ushort pad).
// ---------------------------------------------------------------------------
#define MFMA_CORE(A0PTR, A1PTR, WTPTR)                                         \
  int tid = threadIdx.x;                                                       \
  int lane = tid & 63;                                                         \
  int wave = tid >> 6;                                                         \
  int n15 = lane & 15, quad = lane >> 4;                                       \
  int nb = blockIdx.x * 64;                                                    \
  for (int it = 0; it < 16; ++it) {                                            \
    int i = it * 256 + tid;                                                    \
    int col = i >> 5, c = i & 31;                                              \
    *reinterpret_cast<short8*>(&sB[col * BPAD + c * 8]) =                      \
        reinterpret_cast<const short8*>(WTPTR)[i];                             \
  }                                                                            \
  __syncthreads();                                                             \
  int row = nb + wave * 16 + n15;                                              \
  int arow = (row < NN) ? row : (NN - 1);                                      \
  const ush_t* a0 = A0PTR + (size_t)arow * DD;                                 \
  const ush_t* a1 = A1PTR + (size_t)arow * DD;                                 \
  f32x4 acc[8];                                                                \
  _Pragma("unroll")                                                            \
  for (int t = 0; t < 8; ++t) acc[t] = (f32x4){0.f, 0.f, 0.f, 0.f};           \
  _Pragma("unroll")                                                            \
  for (int c = 0; c < 8; ++c) {                                                \
    const ush_t* ap = (c < 4) ? (a0 + c * 32 + quad * 8)                       \
                              : (a1 + (c - 4) * 32 + quad * 8);                \
    short8 af = *reinterpret_cast<const short8*>(ap);                          \
    int kb = c * 32 + quad * 8;                                                \
    _Pragma("unroll")                                                          \
    for (int t = 0; t < 8; ++t) {                                              \
      short8 bf = *reinterpret_cast<const short8*>(&sB[(t * 16 + n15) * BPAD + kb]); \
      acc[t] = __builtin_amdgcn_mfma_f32_16x16x32_bf16(af, bf, acc[t], 0, 0, 0); \
    }                                                                          \
  }

// ---------------------------------------------------------------------------
// Layer 1: h1 = relu([mean||x] @ Wt1 + bl1), bf16 out.
// C/D: col = lane&15 (+16t), row = quad*4 + reg.
// ---------------------------------------------------------------------------
__global__ __launch_bounds__(256, 2) void sage_l1(
    const ush_t* __restrict__ meanb, const ush_t* __restrict__ xb,
    const ush_t* __restrict__ Wt1, const float* __restrict__ bl,
    ush_t* __restrict__ h1b) {
  __shared__ ush_t sB[128 * BPAD];
  MFMA_CORE(meanb, xb, Wt1)
#pragma unroll
  for (int t = 0; t < 8; ++t) {
    int col = t * 16 + n15;
    float b = bl[col];
#pragma unroll
    for (int reg = 0; reg < 4; ++reg) {
      int r = nb + wave * 16 + quad * 4 + reg;
      if (r < NN)
        h1b[(size_t)r * DD + col] = f2bf(fmaxf(acc[t][reg] + b, 0.f));
    }
  }
}

// ---------------------------------------------------------------------------
// Layer 2 + fused edge projection; s12[i] = (h2[i].We[:128], h2[i].We[128:]).
// ---------------------------------------------------------------------------
__global__ __launch_bounds__(256, 2) void sage_l2(
    const ush_t* __restrict__ meanb, const ush_t* __restrict__ h1b,
    const ush_t* __restrict__ Wt2, const float* __restrict__ bl,
    const float* __restrict__ We, float2* __restrict__ s12) {
  __shared__ ush_t sB[128 * BPAD];
  MFMA_CORE(meanb, h1b, Wt2)
  float p1[4] = {0.f, 0.f, 0.f, 0.f};
  float p2[4] = {0.f, 0.f, 0.f, 0.f};
#pragma unroll
  for (int t = 0; t < 8; ++t) {
    int col = t * 16 + n15;
    float b = bl[col];
    float w1 = We[col];
    float w2 = We[DD + col];
#pragma unroll
    for (int reg = 0; reg < 4; ++reg) {
      float v = acc[t][reg] + b;
      p1[reg] += v * w1;
      p2[reg] += v * w2;
    }
  }
#pragma unroll
  for (int reg = 0; reg < 4; ++reg) {
    float v1 = p1[reg], v2 = p2[reg];
    for (int off = 8; off > 0; off >>= 1) {
      v1 += __shfl_down(v1, off, 16);
      v2 += __shfl_down(v2, off, 16);
    }
    int r = nb + wave * 16 + quad * 4 + reg;
    if (n15 == 0 && r < NN) s12[r] = make_float2(v1, v2);
  }
}

// ---------------------------------------------------------------------------
// Edge scores from compact edges: y = sigmoid(s1[src] + s2[tgt] + be).
// One 4B coalesced edge read + two 8B random (L2-resident) loads per edge.
// ---------------------------------------------------------------------------
__global__ __launch_bounds__(256) void edge_k(const uint_t* __restrict__ epk,
                                              const float2* __restrict__ s12,
                                              const float* __restrict__ be,
                                              float* __restrict__ out) {
  int e = blockIdx.x * 256 + threadIdx.x;
  uint_t p = epk[e];
  float2 a = s12[p & 0xFFFFu];   // src -> need .x (s1)
  float2 b = s12[p >> 16];       // tgt -> need .y (s2)
  float v = a.x + b.y + be[0];
  out[e] = 1.0f / (1.0f + __expf(-v));
}

extern "C" void kernel_launch(void* const* d_in, const int* in_sizes, int n_in,
                              void* d_out, int out_size, void* d_ws, size_t ws_size,
                              hipStream_t stream) {
  const float* x   = (const float*)d_in[0];
  const void*  ei  = d_in[1];
  const float* Wl1 = (const float*)d_in[2];
  const float* bl1 = (const float*)d_in[3];
  const float* Wr1 = (const float*)d_in[4];
  const float* Wl2 = (const float*)d_in[5];
  const float* bl2 = (const float*)d_in[6];
  const float* Wr2 = (const float*)d_in[7];
  const float* We  = (const float*)d_in[8];
  const float* be  = (const float*)d_in[9];
  float* out = (float*)d_out;

  // Workspace (4B units, every section 16B-aligned):
  // bcur[256] | offsets[50004] | epk[NE] | pbuf[BUCKETS*EMAX] | srclist[NE] |
  // xb[NN*DD/2] | meanb | h1b | s12[2*NN] | Wt1[16384] | Wt2[16384]
  int* bcur    = (int*)d_ws;
  int* offsets = bcur + 256;
  uint_t* epk  = (uint_t*)(offsets + 50004);
  uint_t* pbuf = epk + NE;
  int* srclist = (int*)(pbuf + (size_t)BUCKETS * EMAX);
  ush_t* xb    = (ush_t*)(srclist + NE);
  ush_t* meanb = xb + (size_t)NN * DD;
  ush_t* h1b   = meanb + (size_t)NN * DD;
  float2* s12  = (float2*)(h1b + (size_t)NN * DD);
  ush_t* Wt1   = (ush_t*)((float*)s12 + 2 * NN);
  ush_t* Wt2   = Wt1 + 32768;

  hipMemsetAsync(bcur, 0, 256 * sizeof(int), stream);
  prep_part_k<<<PBLK + PACKB + 256, 256, 0, stream>>>(
      ei, bcur, pbuf, epk, x, xb, Wl1, Wr1, Wl2, Wr2, Wt1, Wt2);
  csr_k<<<BUCKETS, 256, 0, stream>>>(pbuf, bcur, offsets, srclist);

  int gemm_blocks = (NN + 63) / 64;  // 782
  agg_k<<<(NN * 16) / 256, 256, 0, stream>>>(xb, srclist, offsets, meanb);
  sage_l1<<<gemm_blocks, 256, 0, stream>>>(meanb, xb, Wt1, bl1, h1b);

  agg_k<<<(NN * 16) / 256, 256, 0, stream>>>(h1b, srclist, offsets, meanb);
  sage_l2<<<gemm_blocks, 256, 0, stream>>>(meanb, h1b, Wt2, bl2, We, s12);

  edge_k<<<NE / 256, 256, 0, stream>>>(epk, s12, be, out);
}